// Round 10
// baseline (6297.292 us; speedup 1.0000x reference)
//
#include <hip/hip_runtime.h>
#include <hip/hip_fp16.h>

// GetTopic: biLSTM (B=32,S=512,W=1024,HP=512) -> fused per-utterance segment
// max -> topic softmax (T=100) -> weighted gather. Inputs fp32 (probe kept).
//
// R16 = R15 (4.52 ms, PROVEN) + ONE delta: k_lstm2 regeometried to 32 WGs
// per dir x 512 threads (8 waves; WG owns 16 units = 64 gate cols). Every
// WG must read the FULL 64 KB h-slab (all-to-all recurrence), so slab
// fabric traffic scales with WG count: 128 WGs x 64 KB = 8 MB/step -> 64
// WGs x 64 KB = 4 MB/step (the measured ~2.3 us/step aggregate-BW term
// halves). Barrier fan-in also halves (32 slots/dir). Per-wave MFMA and
// fragment code byte-identical; R10's VGPR hazard is gone since R15 moved
// the A-operands to LDS (no 128-reg in-flight load arrays).
// Everything else verbatim R15: sc1 h exchange + XOR-swizzled LDS stage,
// slot barrier (4KB spread), LDS-staged wave0 h stores, MFMA xproj,
// deferred mp atomicMax, phased dual-dir execution.

typedef unsigned short u16;
typedef unsigned int   u32;
typedef unsigned long long u64;
typedef __attribute__((ext_vector_type(8))) short short8;
typedef __attribute__((ext_vector_type(4))) float float4v;

__device__ __forceinline__ float bf2f(u16 u) { return __uint_as_float(((u32)u) << 16); }
__device__ __forceinline__ u16 f2bf(float f) {
  u32 u = __float_as_uint(f);
  u32 r = u + 0x7FFFu + ((u >> 16) & 1u);   // RNE
  return (u16)(r >> 16);
}
__device__ __forceinline__ float sigm(float x) { return 1.f / (1.f + expf(-x)); }

__device__ __forceinline__ float ldF(const void* p, size_t i, int isBF) {
  return isBF ? bf2f(((const u16*)p)[i]) : ((const float*)p)[i];
}
__device__ __forceinline__ int ldI(const void* p, int i, int is64) {
  return is64 ? (int)((const u32*)p)[(size_t)2 * i] : ((const int*)p)[i];
}

union U4S8 { uint4 u; short8 s; u16 us[8]; };

// ---------------------------------------------------------------------------
// Probe: input storage formats from raw bits (R4/R5-proven).
// flags[0]: 1 = float tensors bf16, 0 = fp32.  flags[1]: 1 = ids int64.
// ---------------------------------------------------------------------------
__global__ __launch_bounds__(256) void k_probe(
    const u32* __restrict__ X, const u32* __restrict__ U, u32* __restrict__ flags)
{
  __shared__ int cnt[2];
  if (threadIdx.x == 0) { cnt[0] = 0; cnt[1] = 0; }
  __syncthreads();
  int c0 = 0;
  for (int i = threadIdx.x; i < 1024; i += 256) {
    const u32 e = (X[i] >> 7) & 0xFFu;
    if (e >= 112u && e <= 143u) c0++;
  }
  int c1 = 0;
  {
    const u32 w = U[2 * threadIdx.x + 1];
    if (w == 0u || w == 0xFFFFFFFFu) c1++;
  }
  atomicAdd(&cnt[0], c0);
  atomicAdd(&cnt[1], c1);
  __syncthreads();
  if (threadIdx.x == 0) {
    flags[0] = (cnt[0] >= 512) ? 1u : 0u;
    flags[1] = (cnt[1] >= 128) ? 1u : 0u;
  }
}

// ---------------------------------------------------------------------------
// Phase 1: G_local[sl][n][b] = x[s0+sl] @ Wih^T + (bih+bhh) for sl in [0,256).
// R14-proven: split-bf16 MFMA GEMM. M=8192 (m=sl*32+b), N=2048, K=1024.
// ---------------------------------------------------------------------------
__global__ __launch_bounds__(256) void k_xproj(
    const void* __restrict__ X, const void* __restrict__ Wih,
    const void* __restrict__ bih, const void* __restrict__ bhh,
    void* __restrict__ Gv, const u32* __restrict__ flags, int gHalf, int s0)
{
  const int isBF = (int)flags[0];
  const int m0 = blockIdx.x * 64;
  const int n0 = blockIdx.y * 64;
  __shared__ u16 Ah[64][40];   // stride 40 u16 (80B)
  __shared__ u16 Al[64][40];
  __shared__ u16 Bh[64][40];
  __shared__ u16 Bl[64][40];
  const int tid = threadIdx.x;
  const int lrow = tid >> 2;          // 0..63: staging row
  const int lkg  = (tid & 3) * 8;     // k-group of 8 within 32-wide k-tile
  const int lane = tid & 63;
  const int wid  = tid >> 6;          // wave -> M-chunk
  const int l15  = lane & 15;
  const int quad = lane >> 4;
  const int am = m0 + lrow;
  const int ab = am & 31, asl = am >> 5;           // m = sl*32 + b
  const size_t arow = ((size_t)ab * 512 + (s0 + asl)) * 1024;
  const size_t brow = (size_t)(n0 + lrow) * 1024;

  float4v acc[4];
#pragma unroll
  for (int c = 0; c < 4; ++c) {
    acc[c].x = 0.f; acc[c].y = 0.f; acc[c].z = 0.f; acc[c].w = 0.f;
  }

  for (int k0 = 0; k0 < 1024; k0 += 32) {
    float a8[8], b8[8];
    if (isBF) {
      const u16* Xh = (const u16*)X;
      const u16* Wh = (const u16*)Wih;
      uint4 va = *(const uint4*)(Xh + arow + k0 + lkg);
      uint4 vb = *(const uint4*)(Wh + brow + k0 + lkg);
      const u32 wa[4] = {va.x, va.y, va.z, va.w};
      const u32 wb[4] = {vb.x, vb.y, vb.z, vb.w};
#pragma unroll
      for (int q = 0; q < 4; ++q) {
        a8[2 * q]     = __uint_as_float(wa[q] << 16);
        a8[2 * q + 1] = __uint_as_float(wa[q] & 0xFFFF0000u);
        b8[2 * q]     = __uint_as_float(wb[q] << 16);
        b8[2 * q + 1] = __uint_as_float(wb[q] & 0xFFFF0000u);
      }
    } else {
      const float* Xf = (const float*)X;
      const float* Wf = (const float*)Wih;
      const float4 xa0 = *(const float4*)(Xf + arow + k0 + lkg);
      const float4 xa1 = *(const float4*)(Xf + arow + k0 + lkg + 4);
      const float4 xb0 = *(const float4*)(Wf + brow + k0 + lkg);
      const float4 xb1 = *(const float4*)(Wf + brow + k0 + lkg + 4);
      a8[0] = xa0.x; a8[1] = xa0.y; a8[2] = xa0.z; a8[3] = xa0.w;
      a8[4] = xa1.x; a8[5] = xa1.y; a8[6] = xa1.z; a8[7] = xa1.w;
      b8[0] = xb0.x; b8[1] = xb0.y; b8[2] = xb0.z; b8[3] = xb0.w;
      b8[4] = xb1.x; b8[5] = xb1.y; b8[6] = xb1.z; b8[7] = xb1.w;
    }
    U4S8 pah, pal, pbh, pbl;
#pragma unroll
    for (int j = 0; j < 8; ++j) {
      const u16 ah = f2bf(a8[j]);
      pah.us[j] = ah; pal.us[j] = f2bf(a8[j] - bf2f(ah));
      const u16 bh = f2bf(b8[j]);
      pbh.us[j] = bh; pbl.us[j] = f2bf(b8[j] - bf2f(bh));
    }
    *(uint4*)&Ah[lrow][lkg] = pah.u;
    *(uint4*)&Al[lrow][lkg] = pal.u;
    *(uint4*)&Bh[lrow][lkg] = pbh.u;
    *(uint4*)&Bl[lrow][lkg] = pbl.u;
    __syncthreads();

    U4S8 fah, fal;
    fah.u = *(const uint4*)&Ah[wid * 16 + l15][quad * 8];
    fal.u = *(const uint4*)&Al[wid * 16 + l15][quad * 8];
#pragma unroll
    for (int c = 0; c < 4; ++c) {
      U4S8 fbh, fbl;
      fbh.u = *(const uint4*)&Bh[c * 16 + l15][quad * 8];
      fbl.u = *(const uint4*)&Bl[c * 16 + l15][quad * 8];
      acc[c] = __builtin_amdgcn_mfma_f32_16x16x32_bf16(fah.s, fbh.s, acc[c], 0, 0, 0);
      acc[c] = __builtin_amdgcn_mfma_f32_16x16x32_bf16(fah.s, fbl.s, acc[c], 0, 0, 0);
      acc[c] = __builtin_amdgcn_mfma_f32_16x16x32_bf16(fal.s, fbh.s, acc[c], 0, 0, 0);
    }
    __syncthreads();
  }

  const int mrow = m0 + wid * 16 + quad * 4;
  const int b0 = mrow & 31, sl = mrow >> 5;
#pragma unroll
  for (int c = 0; c < 4; ++c) {
    const int n = n0 + c * 16 + l15;
    const float bias = ldF(bih, n, isBF) + ldF(bhh, n, isBF);
    const size_t off = ((size_t)sl * 2048 + n) * 32 + b0;
    if (gHalf) {
      ushort4 pk;
      pk.x = __half_as_ushort(__float2half(acc[c].x + bias));
      pk.y = __half_as_ushort(__float2half(acc[c].y + bias));
      pk.z = __half_as_ushort(__float2half(acc[c].z + bias));
      pk.w = __half_as_ushort(__float2half(acc[c].w + bias));
      *(uint2*)((u16*)Gv + off) = *(uint2*)&pk;
    } else {
      float4 pk;
      pk.x = acc[c].x + bias; pk.y = acc[c].y + bias;
      pk.z = acc[c].z + bias; pk.w = acc[c].w + bias;
      *(float4*)((float*)Gv + off) = pk;
    }
  }
}

// ---------------------------------------------------------------------------
// Phase 2 body. One dir, 32 WGs x 512 threads (8 waves). WG owns 16 hidden
// units = 64 gate cols; Whh resident as split-bf16 MFMA fragments (3 chains
// ~ fp32). Wave (mt=wid&1, nt=wid>>1) computes a 16-batch x 16-col K=512
// tile -- per-wave code identical to R15. Prev-step h slabs (64 KB)
// cooperatively staged into XOR-swizzled LDS once per step.
// ---------------------------------------------------------------------------
__device__ __forceinline__ void lstm_body(
    const int wg, const int dir, const int t0, const int t1, const int s0,
    const void* __restrict__ Gv, const void* __restrict__ Whh,
    u16* __restrict__ Hhi, u16* __restrict__ Hlo, float* __restrict__ Cb,
    float* __restrict__ mp, const void* __restrict__ uid,
    u32* __restrict__ slots, const u32* __restrict__ flags, const int gHalf)
{
  __shared__ float gl[2048];                    // [col64][b32] gate preacts
  __shared__ __align__(16) u16 shh[512];        // staged h hi: [b32][u16]
  __shared__ __align__(16) u16 shl[512];        // staged h lo: [b32][u16]
  __shared__ __align__(16) u16 HhS[16384];      // 32 KB swizzled h-hi slab
  __shared__ __align__(16) u16 HlS[16384];      // 32 KB swizzled h-lo slab
  const int isBF = (int)flags[0];
  const int is64 = (int)flags[1];
  const int tid = threadIdx.x;
  const int j0 = wg * 16;                       // first hidden unit of WG
  const int lane = tid & 63;
  const int wid = tid >> 6;                     // 0..7
  const int mt = wid & 1, nt = wid >> 1;        // batch half / col-16 group
  const int l15 = lane & 15;
  const int quad = lane >> 4;
  const int nl = nt * 16 + l15;                 // col 0..63 within WG
  const int n = ((nl >> 4) * 512) + j0 + (nl & 15);  // global gate row/col

  // B-frags: split-bf16 of Whh row n. B[n=l15][k=quad*8+j].
  short8 bhi[16], blo[16];
#pragma unroll 1
  for (int kt = 0; kt < 16; ++kt) {
    const int k0 = kt * 32 + quad * 8;
    float w[8];
    if (isBF) {
      const u16* Wh = (const u16*)Whh;
#pragma unroll
      for (int jj = 0; jj < 8; ++jj) w[jj] = bf2f(Wh[(size_t)n * 512 + k0 + jj]);
    } else {
      const float* Wf = (const float*)Whh;
      const float4 w0 = *(const float4*)(Wf + (size_t)n * 512 + k0);
      const float4 w1 = *(const float4*)(Wf + (size_t)n * 512 + k0 + 4);
      w[0] = w0.x; w[1] = w0.y; w[2] = w0.z; w[3] = w0.w;
      w[4] = w1.x; w[5] = w1.y; w[6] = w1.z; w[7] = w1.w;
    }
    U4S8 ph, pl;
#pragma unroll
    for (int jj = 0; jj < 8; ++jj) {
      const u16 hi = f2bf(w[jj]);
      const float rem = w[jj] - bf2f(hi);   // exact (Sterbenz)
      ph.us[jj] = hi; pl.us[jj] = f2bf(rem);
    }
    bhi[kt] = ph.s; blo[kt] = pl.s;
  }

  const int b_a = mt * 16 + l15;        // A row = batch
  const int cb = tid & 31;              // consumer: batch
  const int ciu = tid >> 5;             // consumer: unit 0..15
  float c = (t0 == 0) ? 0.f : Cb[cb * 512 + j0 + ciu];

  // Per-thread G column offset; per-step local offset = ls*65536 + gcol.
  const size_t gcol = (size_t)n * 32 + (size_t)(mt * 16 + quad * 4);

  // Prefetch G for t=t0 (plain cached loads -- L2 stays warm).
  float4v gpre;
  {
    const int ls = dir ? (511 - t0 - s0) : (t0 - s0);
    const size_t goff = (size_t)ls * 65536 + gcol;
    if (gHalf) {
      const __half* Gp = (const __half*)Gv;
      gpre.x = __half2float(Gp[goff + 0]);
      gpre.y = __half2float(Gp[goff + 1]);
      gpre.z = __half2float(Gp[goff + 2]);
      gpre.w = __half2float(Gp[goff + 3]);
    } else {
      const float4 gv = *(const float4*)((const float*)Gv + goff);
      gpre.x = gv.x; gpre.y = gv.y; gpre.z = gv.z; gpre.w = gv.w;
    }
  }

  // A-fragment LDS byte offset (swizzled): row b_a, col byte kt*64+quad*16.
  const int abase_sw = b_a * 1024;
  const int aswz = (b_a & 7) << 4;

  for (int t = t0; t < t1; ++t) {
    const int sidx = dir ? (511 - t) : t;
    if (t > t0) {
      // Parallel detection: lanes 0..31 of wave 0 poll 32 spread slots.
      if (tid < 64) {
        const u32 target = (u32)t;
        const u32* sl = slots + (size_t)lane * 1024;   // 4KB stride
        for (;;) {
          const u32 v = (lane < 32)
              ? __hip_atomic_load(sl, __ATOMIC_RELAXED, __HIP_MEMORY_SCOPE_AGENT)
              : target;
          if (__all((int)(v >= target))) break;
          __builtin_amdgcn_s_sleep(1);
        }
      }
      __syncthreads();
    }

    // C-init from prefetched G (4 consecutive batches per lane, col n).
    float4v acc_hh = gpre;
    float4v acc_hl, acc_lh;
    acc_hl.x = 0.f; acc_hl.y = 0.f; acc_hl.z = 0.f; acc_hl.w = 0.f;
    acc_lh.x = 0.f; acc_lh.y = 0.f; acc_lh.z = 0.f; acc_lh.w = 0.f;

    if (t > 0) {
      // Cooperative coalesced stage of prev-step h slabs into LDS.
      // 512 threads x 4 x 16B per slab (contiguous runs), sc1; LDS write
      // uses the read swizzle byte ^= ((row&7)<<4), row = byte>>10.
      const u16* sbh = Hhi + (size_t)((t - 1) & 1) * 16384;
      const u16* sbl = Hlo + (size_t)((t - 1) & 1) * 16384;
      uint4 th[4], tl[4];
#pragma unroll
      for (int j = 0; j < 4; ++j) {
        const u16* ph = sbh + tid * 8 + j * 4096;
        const u16* pl = sbl + tid * 8 + j * 4096;
        asm volatile(
            "global_load_dwordx4 %0, %2, off sc1\n\t"
            "global_load_dwordx4 %1, %3, off sc1"
            : "=v"(th[j]), "=v"(tl[j])
            : "v"(ph), "v"(pl)
            : "memory");
      }
      asm volatile("s_waitcnt vmcnt(0)" ::: "memory");
      __builtin_amdgcn_sched_barrier(0);
#pragma unroll
      for (int j = 0; j < 4; ++j) {
        const int L = tid * 16 + j * 8192;
        const int a = L ^ (((L >> 10) & 7) << 4);
        *(uint4*)((char*)HhS + a) = th[j];
        *(uint4*)((char*)HlS + a) = tl[j];
      }
      __syncthreads();

#pragma unroll
      for (int kt = 0; kt < 16; ++kt) {
        const int aoff = (abase_sw + kt * 64 + quad * 16) ^ aswz;
        U4S8 va, vl;
        va.u = *(const uint4*)((const char*)HhS + aoff);
        vl.u = *(const uint4*)((const char*)HlS + aoff);
        acc_hh = __builtin_amdgcn_mfma_f32_16x16x32_bf16(va.s, bhi[kt], acc_hh, 0, 0, 0);
        acc_hl = __builtin_amdgcn_mfma_f32_16x16x32_bf16(va.s, blo[kt], acc_hl, 0, 0, 0);
        acc_lh = __builtin_amdgcn_mfma_f32_16x16x32_bf16(vl.s, bhi[kt], acc_lh, 0, 0, 0);
      }
    }

    // Prefetch next step's G (independent; hides under exchange + barrier).
    if (t + 1 < t1) {
      const int ls = dir ? (511 - (t + 1) - s0) : (t + 1 - s0);
      const size_t goff = (size_t)ls * 65536 + gcol;
      if (gHalf) {
        const __half* Gp = (const __half*)Gv;
        gpre.x = __half2float(Gp[goff + 0]);
        gpre.y = __half2float(Gp[goff + 1]);
        gpre.z = __half2float(Gp[goff + 2]);
        gpre.w = __half2float(Gp[goff + 3]);
      } else {
        const float4 gv = *(const float4*)((const float*)Gv + goff);
        gpre.x = gv.x; gpre.y = gv.y; gpre.z = gv.z; gpre.w = gv.w;
      }
    }

    // exchange: D row (quad*4+r) = batch - mt*16, col l15 -> nl
    {
      const int base = nl * 32 + mt * 16 + quad * 4;
      gl[base + 0] = acc_hh.x + acc_hl.x + acc_lh.x;
      gl[base + 1] = acc_hh.y + acc_hl.y + acc_lh.y;
      gl[base + 2] = acc_hh.z + acc_hl.z + acc_lh.z;
      gl[base + 3] = acc_hh.w + acc_hl.w + acc_lh.w;
    }
    __syncthreads();

    float hval;
    int id;
    {
      const float a0 = gl[(0 * 16 + ciu) * 32 + cb];
      const float a1 = gl[(1 * 16 + ciu) * 32 + cb];
      const float a2 = gl[(2 * 16 + ciu) * 32 + cb];
      const float a3 = gl[(3 * 16 + ciu) * 32 + cb];
      const float ig = sigm(a0), fg = sigm(a1);
      const float gg = tanhf(a2), og = sigm(a3);
      c = fg * c + ig * gg;
      hval = og * tanhf(c);
      const u16 hh = f2bf(hval);
      shh[cb * 16 + ciu] = hh;
      shl[cb * 16 + ciu] = f2bf(hval - bf2f(hh));
      id = ldI(uid, cb * 512 + sidx, is64);
    }
    __syncthreads();

    // Wave 0: re-gather staged h, 256x 8B agent stores (16B runs/batch/slab),
    // one drain, tid0 publishes. Other waves proceed to atomicMax.
    if (tid < 64) {
      const int sb = lane >> 1, q = lane & 1;       // batch, 8-unit chunk
      const u64* srcH = (const u64*)shh;
      const u64* srcL = (const u64*)shl;
      const u64 vh0 = srcH[sb * 4 + q * 2];
      const u64 vh1 = srcH[sb * 4 + q * 2 + 1];
      const u64 vl0 = srcL[sb * 4 + q * 2];
      const u64 vl1 = srcL[sb * 4 + q * 2 + 1];
      const size_t so = (size_t)(t & 1) * 16384 + (size_t)sb * 512 + j0 + q * 8;
      __hip_atomic_store((u64*)(Hhi + so) + 0, vh0, __ATOMIC_RELAXED, __HIP_MEMORY_SCOPE_AGENT);
      __hip_atomic_store((u64*)(Hhi + so) + 1, vh1, __ATOMIC_RELAXED, __HIP_MEMORY_SCOPE_AGENT);
      __hip_atomic_store((u64*)(Hlo + so) + 0, vl0, __ATOMIC_RELAXED, __HIP_MEMORY_SCOPE_AGENT);
      __hip_atomic_store((u64*)(Hlo + so) + 1, vl1, __ATOMIC_RELAXED, __HIP_MEMORY_SCOPE_AGENT);
      asm volatile("s_waitcnt vmcnt(0)" ::: "memory");
      if (tid == 0)
        __hip_atomic_store(slots + (size_t)wg * 1024, (u32)(t + 1),
                           __ATOMIC_RELAXED, __HIP_MEMORY_SCOPE_AGENT);
    }
    // Deferred fused max-pool: overlaps the next poll.
    if (id > 0 && hval > 0.f)
      atomicMax((int*)&mp[(size_t)(cb * 32 + (id - 1)) * 1024 + dir * 512 + (j0 + ciu)],
                __float_as_int(hval));
  }

  if (t1 < 512) Cb[cb * 512 + j0 + ciu] = c;   // spill c across phase boundary
}

// Fused dual-direction phase kernel: WGs 0..31 = dir0, 32..63 = dir1.
__global__ __launch_bounds__(512) void k_lstm2(
    const void* __restrict__ GA, const void* __restrict__ GB,
    const void* __restrict__ WhhA, const void* __restrict__ WhhB,
    u16* __restrict__ Hh0, u16* __restrict__ Hl0,
    u16* __restrict__ Hh1, u16* __restrict__ Hl1,
    float* __restrict__ Cb, float* __restrict__ mp,
    const void* __restrict__ uid, u32* __restrict__ slots,
    const u32* __restrict__ flags, int gHalf,
    int t0, int t1, int s0A, int s0B)
{
  const int dir = ((int)blockIdx.x >= 32) ? 1 : 0;
  const int wg = (int)blockIdx.x & 31;
  const void* Gv  = dir ? GB : GA;
  const void* Whh = dir ? WhhB : WhhA;
  u16* Hhi = dir ? Hh1 : Hh0;
  u16* Hlo = dir ? Hl1 : Hl0;
  lstm_body(wg, dir, t0, t1, dir ? s0B : s0A, Gv, Whh, Hhi, Hlo,
            Cb + (size_t)dir * 16384, mp, uid,
            slots + (size_t)dir * 65536, flags, gHalf);
}

// ---------------------------------------------------------------------------
// Phase 4a: topic_weights -> twT[k][t] fp32, bias -> fp32.
// ---------------------------------------------------------------------------
__global__ __launch_bounds__(256) void k_prep(
    const void* __restrict__ tw, const void* __restrict__ tb,
    float* __restrict__ twT, float* __restrict__ biasT, const u32* __restrict__ flags)
{
  const int isBF = (int)flags[0];
  const int idx = blockIdx.x * 256 + threadIdx.x;
  if (idx < 102400) {
    const int t = idx >> 10, k = idx & 1023;
    twT[k * 100 + t] = ldF(tw, idx, isBF);
  } else if (idx < 102500) {
    biasT[idx - 102400] = ldF(tb, idx - 102400, isBF);
  }
}

// ---------------------------------------------------------------------------
// Phase 4: per (b,u): logits(100) -> softmax -> emb row (fp32).
// ---------------------------------------------------------------------------
__global__ __launch_bounds__(256) void k_topic(
    const float* __restrict__ mp, const float* __restrict__ twT,
    const float* __restrict__ biasT, const void* __restrict__ table,
    float* __restrict__ emb, const u32* __restrict__ flags)
{
  const int isBF = (int)flags[0];
  const int bu = blockIdx.x;
  const int tid = threadIdx.x;
  __shared__ float lrow[1024];
  __shared__ float red[128];
  __shared__ float parr[128];
  for (int i = tid; i < 1024; i += 256) lrow[i] = mp[(size_t)bu * 1024 + i];
  __syncthreads();
  float lacc = -1e30f;
  if (tid < 100) {
    lacc = biasT[tid];
    for (int k = 0; k < 1024; ++k) lacc = fmaf(lrow[k], twT[k * 100 + tid], lacc);
  }
  if (tid < 128) red[tid] = (tid < 100) ? lacc : -1e30f;
  __syncthreads();
  for (int off = 64; off > 0; off >>= 1) {
    if (tid < off) red[tid] = fmaxf(red[tid], red[tid + off]);
    __syncthreads();
  }
  const float mxv = red[0];
  __syncthreads();
  const float e = (tid < 100) ? expf(lacc - mxv) : 0.f;
  if (tid < 128) red[tid] = e;
  __syncthreads();
  for (int off = 64; off > 0; off >>= 1) {
    if (tid < off) red[tid] += red[tid + off];
    __syncthreads();
  }
  const float inv = 1.f / red[0];
  if (tid < 128) parr[tid] = e * inv;
  __syncthreads();
#pragma unroll
  for (int r = 0; r < 4; ++r) {
    const int w = tid + 256 * r;
    float a = 0.f;
    for (int t = 0; t < 100; ++t)
      a = fmaf(parr[t], ldF(table, (size_t)t * 1024 + w, isBF), a);
    emb[(size_t)bu * 1024 + w] = a;
  }
}

// ---------------------------------------------------------------------------
// Phase 5: out = emb[b][clip(|uid|-1,0,31)][w] * {1,2,0}. Dtype by flag.
// ---------------------------------------------------------------------------
__global__ __launch_bounds__(256) void k_out(
    const float* __restrict__ emb, const void* __restrict__ uid,
    void* __restrict__ outv, const u32* __restrict__ flags)
{
  const int isBF = (int)flags[0];
  const int is64 = (int)flags[1];
  const int idx = blockIdx.x * 256 + threadIdx.x;
  const int w = idx & 1023;
  const int s = (idx >> 10) & 511;
  const int b = idx >> 19;
  const int id = ldI(uid, b * 512 + s, is64);
  const float wt = (id > 0) ? 1.f : ((id < 0) ? 2.f : 0.f);
  int au = (id < 0) ? (-id - 1) : (id - 1);
  au = max(0, min(31, au));
  const float v = emb[(size_t)(b * 32 + au) * 1024 + w] * wt;
  if (isBF) ((u16*)outv)[idx] = f2bf(v);
  else      ((float*)outv)[idx] = v;
}

// ---------------------------------------------------------------------------
// ws layout (phased fused dirs):
//  fp32-G (ws >= 143,934,464; R5 proved >=176.7MB):
//    GA 64Mi | GB 64Mi | Hh0,Hl0,Hh1,Hl1 4x64Ki | Cb 128Ki | mp 4Mi | emb 4Mi
//    | twT 400Ki | biasT 512 | slots 512Ki (2 dirs x 32 x 4KB) | flags 512
//  fp16-G fallback: GA/GB 32Mi each + same tail ~= 76.8 MB
// ---------------------------------------------------------------------------
extern "C" void kernel_launch(void* const* d_in, const int* in_sizes, int n_in,
                              void* d_out, int out_size, void* d_ws, size_t ws_size,
                              hipStream_t stream) {
  (void)in_sizes; (void)n_in; (void)out_size;
  const void* X    = d_in[0];
  const void* uid  = d_in[1];
  const void* Wihf = d_in[2];
  const void* Whhf = d_in[3];
  const void* bihf = d_in[4];
  const void* bhhf = d_in[5];
  const void* Wihb = d_in[6];
  const void* Whhb = d_in[7];
  const void* bihb = d_in[8];
  const void* bhhb = d_in[9];
  const void* tw   = d_in[10];
  const void* tb   = d_in[11];
  const void* tt   = d_in[12];
  char* ws = (char*)d_ws;

  const int gHalf = (ws_size >= 143934464ull) ? 0 : 1;
  const size_t gB = gHalf ? 33554432ull : 67108864ull;   // per-dir G (256 steps)
  const size_t oGB = gB;
  const size_t oH  = 2ull * gB;
  const size_t oCb = oH + 262144ull;          // 4 slabs x 64Ki
  const size_t omp = oCb + 131072ull;
  const size_t oem = omp + 4194304ull;
  const size_t otw = oem + 4194304ull;
  const size_t obi = otw + 409600ull;
  const size_t osl = obi + 512ull;
  const size_t oFL = osl + 524288ull;

  void*  GA    = (void*)(ws + 0);
  void*  GB    = (void*)(ws + oGB);
  u16*   Hh0   = (u16*)(ws + oH);
  u16*   Hl0   = (u16*)(ws + oH + 65536ull);
  u16*   Hh1   = (u16*)(ws + oH + 131072ull);
  u16*   Hl1   = (u16*)(ws + oH + 196608ull);
  float* Cb    = (float*)(ws + oCb);
  float* mp    = (float*)(ws + omp);
  float* emb   = (float*)(ws + oem);
  float* twT   = (float*)(ws + otw);
  float* biasT = (float*)(ws + obi);
  u32*   slots = (u32*)(ws + osl);
  u32*   flags = (u32*)(ws + oFL);

  (void)hipMemsetAsync(mp, 0, 4194304ull, stream);    // segment-max floor = 0
  (void)hipMemsetAsync(slots, 0, 524288ull, stream);  // barrier slots (spread)
  k_probe<<<1, 256, 0, stream>>>((const u32*)X, (const u32*)uid, flags);

  // Phase A: dir0 s[0,256) -> GA; dir1 s[256,512) -> GB; steps t=0..255.
  k_xproj<<<dim3(128, 32), 256, 0, stream>>>(X, Wihf, bihf, bhhf, GA, flags, gHalf, 0);
  k_xproj<<<dim3(128, 32), 256, 0, stream>>>(X, Wihb, bihb, bhhb, GB, flags, gHalf, 256);
  k_lstm2<<<64, 512, 0, stream>>>(GA, GB, Whhf, Whhb, Hh0, Hl0, Hh1, Hl1,
                                  Cb, mp, uid, slots, flags, gHalf,
                                  0, 256, 0, 256);
  // Phase B: dir0 s[256,512) -> GA; dir1 s[0,256) -> GB; steps t=256..511.
  k_xproj<<<dim3(128, 32), 256, 0, stream>>>(X, Wihf, bihf, bhhf, GA, flags, gHalf, 256);
  k_xproj<<<dim3(128, 32), 256, 0, stream>>>(X, Wihb, bihb, bhhb, GB, flags, gHalf, 0);
  k_lstm2<<<64, 512, 0, stream>>>(GA, GB, Whhf, Whhb, Hh0, Hl0, Hh1, Hl1,
                                  Cb, mp, uid, slots, flags, gHalf,
                                  256, 512, 256, 0);

  k_prep<<<401, 256, 0, stream>>>(tw, tb, twT, biasT, flags);
  k_topic<<<1024, 256, 0, stream>>>(mp, twT, biasT, tt, emb, flags);
  k_out<<<65536, 256, 0, stream>>>(emb, uid, d_out, flags);
}

// Round 11
// 6289.017 us; speedup vs baseline: 1.0013x; 1.0013x over previous
//
#include <hip/hip_runtime.h>
#include <hip/hip_fp16.h>

// GetTopic: biLSTM (B=32,S=512,W=1024,HP=512) -> fused per-utterance segment
// max -> topic softmax (T=100) -> weighted gather. Inputs fp32 (probe kept).
//
// R17 = R16 + ONE line: __launch_bounds__(512, 2) on k_lstm2. R16 regressed
// (2680 vs R15's 1810 us) because VGPR_Count=52 proves the 128-VGPR
// bhi/blo Whh fragment arrays were SPILLED TO SCRATCH (launch_bounds(512)
// defaulted to a small register budget) -> ~16 MB/step scratch re-reads.
// min-2-waves/EU raises the budget to 256 VGPRs; true demand ~200 -> no
// spill, and R16's geometry theory (halved slab fabric traffic: 64 WGs x
// 64 KB = 4 MB/step; halved barrier fan-in) gets its fair test.
// Everything else verbatim R16/R15: sc1 h exchange + XOR-swizzled LDS
// stage, slot barrier (4KB spread), LDS-staged wave0 h stores, MFMA xproj,
// deferred mp atomicMax, phased dual-dir execution.

typedef unsigned short u16;
typedef unsigned int   u32;
typedef unsigned long long u64;
typedef __attribute__((ext_vector_type(8))) short short8;
typedef __attribute__((ext_vector_type(4))) float float4v;

__device__ __forceinline__ float bf2f(u16 u) { return __uint_as_float(((u32)u) << 16); }
__device__ __forceinline__ u16 f2bf(float f) {
  u32 u = __float_as_uint(f);
  u32 r = u + 0x7FFFu + ((u >> 16) & 1u);   // RNE
  return (u16)(r >> 16);
}
__device__ __forceinline__ float sigm(float x) { return 1.f / (1.f + expf(-x)); }

__device__ __forceinline__ float ldF(const void* p, size_t i, int isBF) {
  return isBF ? bf2f(((const u16*)p)[i]) : ((const float*)p)[i];
}
__device__ __forceinline__ int ldI(const void* p, int i, int is64) {
  return is64 ? (int)((const u32*)p)[(size_t)2 * i] : ((const int*)p)[i];
}

union U4S8 { uint4 u; short8 s; u16 us[8]; };

// ---------------------------------------------------------------------------
// Probe: input storage formats from raw bits (R4/R5-proven).
// flags[0]: 1 = float tensors bf16, 0 = fp32.  flags[1]: 1 = ids int64.
// ---------------------------------------------------------------------------
__global__ __launch_bounds__(256) void k_probe(
    const u32* __restrict__ X, const u32* __restrict__ U, u32* __restrict__ flags)
{
  __shared__ int cnt[2];
  if (threadIdx.x == 0) { cnt[0] = 0; cnt[1] = 0; }
  __syncthreads();
  int c0 = 0;
  for (int i = threadIdx.x; i < 1024; i += 256) {
    const u32 e = (X[i] >> 7) & 0xFFu;
    if (e >= 112u && e <= 143u) c0++;
  }
  int c1 = 0;
  {
    const u32 w = U[2 * threadIdx.x + 1];
    if (w == 0u || w == 0xFFFFFFFFu) c1++;
  }
  atomicAdd(&cnt[0], c0);
  atomicAdd(&cnt[1], c1);
  __syncthreads();
  if (threadIdx.x == 0) {
    flags[0] = (cnt[0] >= 512) ? 1u : 0u;
    flags[1] = (cnt[1] >= 128) ? 1u : 0u;
  }
}

// ---------------------------------------------------------------------------
// Phase 1: G_local[sl][n][b] = x[s0+sl] @ Wih^T + (bih+bhh) for sl in [0,256).
// R14-proven: split-bf16 MFMA GEMM. M=8192 (m=sl*32+b), N=2048, K=1024.
// ---------------------------------------------------------------------------
__global__ __launch_bounds__(256) void k_xproj(
    const void* __restrict__ X, const void* __restrict__ Wih,
    const void* __restrict__ bih, const void* __restrict__ bhh,
    void* __restrict__ Gv, const u32* __restrict__ flags, int gHalf, int s0)
{
  const int isBF = (int)flags[0];
  const int m0 = blockIdx.x * 64;
  const int n0 = blockIdx.y * 64;
  __shared__ u16 Ah[64][40];   // stride 40 u16 (80B)
  __shared__ u16 Al[64][40];
  __shared__ u16 Bh[64][40];
  __shared__ u16 Bl[64][40];
  const int tid = threadIdx.x;
  const int lrow = tid >> 2;          // 0..63: staging row
  const int lkg  = (tid & 3) * 8;     // k-group of 8 within 32-wide k-tile
  const int lane = tid & 63;
  const int wid  = tid >> 6;          // wave -> M-chunk
  const int l15  = lane & 15;
  const int quad = lane >> 4;
  const int am = m0 + lrow;
  const int ab = am & 31, asl = am >> 5;           // m = sl*32 + b
  const size_t arow = ((size_t)ab * 512 + (s0 + asl)) * 1024;
  const size_t brow = (size_t)(n0 + lrow) * 1024;

  float4v acc[4];
#pragma unroll
  for (int c = 0; c < 4; ++c) {
    acc[c].x = 0.f; acc[c].y = 0.f; acc[c].z = 0.f; acc[c].w = 0.f;
  }

  for (int k0 = 0; k0 < 1024; k0 += 32) {
    float a8[8], b8[8];
    if (isBF) {
      const u16* Xh = (const u16*)X;
      const u16* Wh = (const u16*)Wih;
      uint4 va = *(const uint4*)(Xh + arow + k0 + lkg);
      uint4 vb = *(const uint4*)(Wh + brow + k0 + lkg);
      const u32 wa[4] = {va.x, va.y, va.z, va.w};
      const u32 wb[4] = {vb.x, vb.y, vb.z, vb.w};
#pragma unroll
      for (int q = 0; q < 4; ++q) {
        a8[2 * q]     = __uint_as_float(wa[q] << 16);
        a8[2 * q + 1] = __uint_as_float(wa[q] & 0xFFFF0000u);
        b8[2 * q]     = __uint_as_float(wb[q] << 16);
        b8[2 * q + 1] = __uint_as_float(wb[q] & 0xFFFF0000u);
      }
    } else {
      const float* Xf = (const float*)X;
      const float* Wf = (const float*)Wih;
      const float4 xa0 = *(const float4*)(Xf + arow + k0 + lkg);
      const float4 xa1 = *(const float4*)(Xf + arow + k0 + lkg + 4);
      const float4 xb0 = *(const float4*)(Wf + brow + k0 + lkg);
      const float4 xb1 = *(const float4*)(Wf + brow + k0 + lkg + 4);
      a8[0] = xa0.x; a8[1] = xa0.y; a8[2] = xa0.z; a8[3] = xa0.w;
      a8[4] = xa1.x; a8[5] = xa1.y; a8[6] = xa1.z; a8[7] = xa1.w;
      b8[0] = xb0.x; b8[1] = xb0.y; b8[2] = xb0.z; b8[3] = xb0.w;
      b8[4] = xb1.x; b8[5] = xb1.y; b8[6] = xb1.z; b8[7] = xb1.w;
    }
    U4S8 pah, pal, pbh, pbl;
#pragma unroll
    for (int j = 0; j < 8; ++j) {
      const u16 ah = f2bf(a8[j]);
      pah.us[j] = ah; pal.us[j] = f2bf(a8[j] - bf2f(ah));
      const u16 bh = f2bf(b8[j]);
      pbh.us[j] = bh; pbl.us[j] = f2bf(b8[j] - bf2f(bh));
    }
    *(uint4*)&Ah[lrow][lkg] = pah.u;
    *(uint4*)&Al[lrow][lkg] = pal.u;
    *(uint4*)&Bh[lrow][lkg] = pbh.u;
    *(uint4*)&Bl[lrow][lkg] = pbl.u;
    __syncthreads();

    U4S8 fah, fal;
    fah.u = *(const uint4*)&Ah[wid * 16 + l15][quad * 8];
    fal.u = *(const uint4*)&Al[wid * 16 + l15][quad * 8];
#pragma unroll
    for (int c = 0; c < 4; ++c) {
      U4S8 fbh, fbl;
      fbh.u = *(const uint4*)&Bh[c * 16 + l15][quad * 8];
      fbl.u = *(const uint4*)&Bl[c * 16 + l15][quad * 8];
      acc[c] = __builtin_amdgcn_mfma_f32_16x16x32_bf16(fah.s, fbh.s, acc[c], 0, 0, 0);
      acc[c] = __builtin_amdgcn_mfma_f32_16x16x32_bf16(fah.s, fbl.s, acc[c], 0, 0, 0);
      acc[c] = __builtin_amdgcn_mfma_f32_16x16x32_bf16(fal.s, fbh.s, acc[c], 0, 0, 0);
    }
    __syncthreads();
  }

  const int mrow = m0 + wid * 16 + quad * 4;
  const int b0 = mrow & 31, sl = mrow >> 5;
#pragma unroll
  for (int c = 0; c < 4; ++c) {
    const int n = n0 + c * 16 + l15;
    const float bias = ldF(bih, n, isBF) + ldF(bhh, n, isBF);
    const size_t off = ((size_t)sl * 2048 + n) * 32 + b0;
    if (gHalf) {
      ushort4 pk;
      pk.x = __half_as_ushort(__float2half(acc[c].x + bias));
      pk.y = __half_as_ushort(__float2half(acc[c].y + bias));
      pk.z = __half_as_ushort(__float2half(acc[c].z + bias));
      pk.w = __half_as_ushort(__float2half(acc[c].w + bias));
      *(uint2*)((u16*)Gv + off) = *(uint2*)&pk;
    } else {
      float4 pk;
      pk.x = acc[c].x + bias; pk.y = acc[c].y + bias;
      pk.z = acc[c].z + bias; pk.w = acc[c].w + bias;
      *(float4*)((float*)Gv + off) = pk;
    }
  }
}

// ---------------------------------------------------------------------------
// Phase 2 body. One dir, 32 WGs x 512 threads (8 waves). WG owns 16 hidden
// units = 64 gate cols; Whh resident as split-bf16 MFMA fragments (3 chains
// ~ fp32). Wave (mt=wid&1, nt=wid>>1) computes a 16-batch x 16-col K=512
// tile. Prev-step h slabs (64 KB) cooperatively staged into XOR-swizzled
// LDS once per step.
// ---------------------------------------------------------------------------
__device__ __forceinline__ void lstm_body(
    const int wg, const int dir, const int t0, const int t1, const int s0,
    const void* __restrict__ Gv, const void* __restrict__ Whh,
    u16* __restrict__ Hhi, u16* __restrict__ Hlo, float* __restrict__ Cb,
    float* __restrict__ mp, const void* __restrict__ uid,
    u32* __restrict__ slots, const u32* __restrict__ flags, const int gHalf)
{
  __shared__ float gl[2048];                    // [col64][b32] gate preacts
  __shared__ __align__(16) u16 shh[512];        // staged h hi: [b32][u16]
  __shared__ __align__(16) u16 shl[512];        // staged h lo: [b32][u16]
  __shared__ __align__(16) u16 HhS[16384];      // 32 KB swizzled h-hi slab
  __shared__ __align__(16) u16 HlS[16384];      // 32 KB swizzled h-lo slab
  const int isBF = (int)flags[0];
  const int is64 = (int)flags[1];
  const int tid = threadIdx.x;
  const int j0 = wg * 16;                       // first hidden unit of WG
  const int lane = tid & 63;
  const int wid = tid >> 6;                     // 0..7
  const int mt = wid & 1, nt = wid >> 1;        // batch half / col-16 group
  const int l15 = lane & 15;
  const int quad = lane >> 4;
  const int nl = nt * 16 + l15;                 // col 0..63 within WG
  const int n = ((nl >> 4) * 512) + j0 + (nl & 15);  // global gate row/col

  // B-frags: split-bf16 of Whh row n. B[n=l15][k=quad*8+j].
  short8 bhi[16], blo[16];
#pragma unroll 1
  for (int kt = 0; kt < 16; ++kt) {
    const int k0 = kt * 32 + quad * 8;
    float w[8];
    if (isBF) {
      const u16* Wh = (const u16*)Whh;
#pragma unroll
      for (int jj = 0; jj < 8; ++jj) w[jj] = bf2f(Wh[(size_t)n * 512 + k0 + jj]);
    } else {
      const float* Wf = (const float*)Whh;
      const float4 w0 = *(const float4*)(Wf + (size_t)n * 512 + k0);
      const float4 w1 = *(const float4*)(Wf + (size_t)n * 512 + k0 + 4);
      w[0] = w0.x; w[1] = w0.y; w[2] = w0.z; w[3] = w0.w;
      w[4] = w1.x; w[5] = w1.y; w[6] = w1.z; w[7] = w1.w;
    }
    U4S8 ph, pl;
#pragma unroll
    for (int jj = 0; jj < 8; ++jj) {
      const u16 hi = f2bf(w[jj]);
      const float rem = w[jj] - bf2f(hi);   // exact (Sterbenz)
      ph.us[jj] = hi; pl.us[jj] = f2bf(rem);
    }
    bhi[kt] = ph.s; blo[kt] = pl.s;
  }

  const int b_a = mt * 16 + l15;        // A row = batch
  const int cb = tid & 31;              // consumer: batch
  const int ciu = tid >> 5;             // consumer: unit 0..15
  float c = (t0 == 0) ? 0.f : Cb[cb * 512 + j0 + ciu];

  // Per-thread G column offset; per-step local offset = ls*65536 + gcol.
  const size_t gcol = (size_t)n * 32 + (size_t)(mt * 16 + quad * 4);

  // Prefetch G for t=t0 (plain cached loads -- L2 stays warm).
  float4v gpre;
  {
    const int ls = dir ? (511 - t0 - s0) : (t0 - s0);
    const size_t goff = (size_t)ls * 65536 + gcol;
    if (gHalf) {
      const __half* Gp = (const __half*)Gv;
      gpre.x = __half2float(Gp[goff + 0]);
      gpre.y = __half2float(Gp[goff + 1]);
      gpre.z = __half2float(Gp[goff + 2]);
      gpre.w = __half2float(Gp[goff + 3]);
    } else {
      const float4 gv = *(const float4*)((const float*)Gv + goff);
      gpre.x = gv.x; gpre.y = gv.y; gpre.z = gv.z; gpre.w = gv.w;
    }
  }

  // A-fragment LDS byte offset (swizzled): row b_a, col byte kt*64+quad*16.
  const int abase_sw = b_a * 1024;
  const int aswz = (b_a & 7) << 4;

  for (int t = t0; t < t1; ++t) {
    const int sidx = dir ? (511 - t) : t;
    if (t > t0) {
      // Parallel detection: lanes 0..31 of wave 0 poll 32 spread slots.
      if (tid < 64) {
        const u32 target = (u32)t;
        const u32* sl = slots + (size_t)lane * 1024;   // 4KB stride
        for (;;) {
          const u32 v = (lane < 32)
              ? __hip_atomic_load(sl, __ATOMIC_RELAXED, __HIP_MEMORY_SCOPE_AGENT)
              : target;
          if (__all((int)(v >= target))) break;
          __builtin_amdgcn_s_sleep(1);
        }
      }
      __syncthreads();
    }

    // C-init from prefetched G (4 consecutive batches per lane, col n).
    float4v acc_hh = gpre;
    float4v acc_hl, acc_lh;
    acc_hl.x = 0.f; acc_hl.y = 0.f; acc_hl.z = 0.f; acc_hl.w = 0.f;
    acc_lh.x = 0.f; acc_lh.y = 0.f; acc_lh.z = 0.f; acc_lh.w = 0.f;

    if (t > 0) {
      // Cooperative coalesced stage of prev-step h slabs into LDS.
      // 512 threads x 4 x 16B per slab (contiguous runs), sc1; LDS write
      // uses the read swizzle byte ^= ((row&7)<<4), row = byte>>10.
      const u16* sbh = Hhi + (size_t)((t - 1) & 1) * 16384;
      const u16* sbl = Hlo + (size_t)((t - 1) & 1) * 16384;
      uint4 th[4], tl[4];
#pragma unroll
      for (int j = 0; j < 4; ++j) {
        const u16* ph = sbh + tid * 8 + j * 4096;
        const u16* pl = sbl + tid * 8 + j * 4096;
        asm volatile(
            "global_load_dwordx4 %0, %2, off sc1\n\t"
            "global_load_dwordx4 %1, %3, off sc1"
            : "=v"(th[j]), "=v"(tl[j])
            : "v"(ph), "v"(pl)
            : "memory");
      }
      asm volatile("s_waitcnt vmcnt(0)" ::: "memory");
      __builtin_amdgcn_sched_barrier(0);
#pragma unroll
      for (int j = 0; j < 4; ++j) {
        const int L = tid * 16 + j * 8192;
        const int a = L ^ (((L >> 10) & 7) << 4);
        *(uint4*)((char*)HhS + a) = th[j];
        *(uint4*)((char*)HlS + a) = tl[j];
      }
      __syncthreads();

#pragma unroll
      for (int kt = 0; kt < 16; ++kt) {
        const int aoff = (abase_sw + kt * 64 + quad * 16) ^ aswz;
        U4S8 va, vl;
        va.u = *(const uint4*)((const char*)HhS + aoff);
        vl.u = *(const uint4*)((const char*)HlS + aoff);
        acc_hh = __builtin_amdgcn_mfma_f32_16x16x32_bf16(va.s, bhi[kt], acc_hh, 0, 0, 0);
        acc_hl = __builtin_amdgcn_mfma_f32_16x16x32_bf16(va.s, blo[kt], acc_hl, 0, 0, 0);
        acc_lh = __builtin_amdgcn_mfma_f32_16x16x32_bf16(vl.s, bhi[kt], acc_lh, 0, 0, 0);
      }
    }

    // Prefetch next step's G (independent; hides under exchange + barrier).
    if (t + 1 < t1) {
      const int ls = dir ? (511 - (t + 1) - s0) : (t + 1 - s0);
      const size_t goff = (size_t)ls * 65536 + gcol;
      if (gHalf) {
        const __half* Gp = (const __half*)Gv;
        gpre.x = __half2float(Gp[goff + 0]);
        gpre.y = __half2float(Gp[goff + 1]);
        gpre.z = __half2float(Gp[goff + 2]);
        gpre.w = __half2float(Gp[goff + 3]);
      } else {
        const float4 gv = *(const float4*)((const float*)Gv + goff);
        gpre.x = gv.x; gpre.y = gv.y; gpre.z = gv.z; gpre.w = gv.w;
      }
    }

    // exchange: D row (quad*4+r) = batch - mt*16, col l15 -> nl
    {
      const int base = nl * 32 + mt * 16 + quad * 4;
      gl[base + 0] = acc_hh.x + acc_hl.x + acc_lh.x;
      gl[base + 1] = acc_hh.y + acc_hl.y + acc_lh.y;
      gl[base + 2] = acc_hh.z + acc_hl.z + acc_lh.z;
      gl[base + 3] = acc_hh.w + acc_hl.w + acc_lh.w;
    }
    __syncthreads();

    float hval;
    int id;
    {
      const float a0 = gl[(0 * 16 + ciu) * 32 + cb];
      const float a1 = gl[(1 * 16 + ciu) * 32 + cb];
      const float a2 = gl[(2 * 16 + ciu) * 32 + cb];
      const float a3 = gl[(3 * 16 + ciu) * 32 + cb];
      const float ig = sigm(a0), fg = sigm(a1);
      const float gg = tanhf(a2), og = sigm(a3);
      c = fg * c + ig * gg;
      hval = og * tanhf(c);
      const u16 hh = f2bf(hval);
      shh[cb * 16 + ciu] = hh;
      shl[cb * 16 + ciu] = f2bf(hval - bf2f(hh));
      id = ldI(uid, cb * 512 + sidx, is64);
    }
    __syncthreads();

    // Wave 0: re-gather staged h, 256x 8B agent stores (16B runs/batch/slab),
    // one drain, tid0 publishes. Other waves proceed to atomicMax.
    if (tid < 64) {
      const int sb = lane >> 1, q = lane & 1;       // batch, 8-unit chunk
      const u64* srcH = (const u64*)shh;
      const u64* srcL = (const u64*)shl;
      const u64 vh0 = srcH[sb * 4 + q * 2];
      const u64 vh1 = srcH[sb * 4 + q * 2 + 1];
      const u64 vl0 = srcL[sb * 4 + q * 2];
      const u64 vl1 = srcL[sb * 4 + q * 2 + 1];
      const size_t so = (size_t)(t & 1) * 16384 + (size_t)sb * 512 + j0 + q * 8;
      __hip_atomic_store((u64*)(Hhi + so) + 0, vh0, __ATOMIC_RELAXED, __HIP_MEMORY_SCOPE_AGENT);
      __hip_atomic_store((u64*)(Hhi + so) + 1, vh1, __ATOMIC_RELAXED, __HIP_MEMORY_SCOPE_AGENT);
      __hip_atomic_store((u64*)(Hlo + so) + 0, vl0, __ATOMIC_RELAXED, __HIP_MEMORY_SCOPE_AGENT);
      __hip_atomic_store((u64*)(Hlo + so) + 1, vl1, __ATOMIC_RELAXED, __HIP_MEMORY_SCOPE_AGENT);
      asm volatile("s_waitcnt vmcnt(0)" ::: "memory");
      if (tid == 0)
        __hip_atomic_store(slots + (size_t)wg * 1024, (u32)(t + 1),
                           __ATOMIC_RELAXED, __HIP_MEMORY_SCOPE_AGENT);
    }
    // Deferred fused max-pool: overlaps the next poll.
    if (id > 0 && hval > 0.f)
      atomicMax((int*)&mp[(size_t)(cb * 32 + (id - 1)) * 1024 + dir * 512 + (j0 + ciu)],
                __float_as_int(hval));
  }

  if (t1 < 512) Cb[cb * 512 + j0 + ciu] = c;   // spill c across phase boundary
}

// Fused dual-direction phase kernel: WGs 0..31 = dir0, 32..63 = dir1.
// __launch_bounds__(512, 2): 8 waves/WG = 2 waves/SIMD -> 256-VGPR budget
// (R16's default cap spilled the 128-VGPR Whh fragment arrays to scratch).
__global__ __launch_bounds__(512, 2) void k_lstm2(
    const void* __restrict__ GA, const void* __restrict__ GB,
    const void* __restrict__ WhhA, const void* __restrict__ WhhB,
    u16* __restrict__ Hh0, u16* __restrict__ Hl0,
    u16* __restrict__ Hh1, u16* __restrict__ Hl1,
    float* __restrict__ Cb, float* __restrict__ mp,
    const void* __restrict__ uid, u32* __restrict__ slots,
    const u32* __restrict__ flags, int gHalf,
    int t0, int t1, int s0A, int s0B)
{
  const int dir = ((int)blockIdx.x >= 32) ? 1 : 0;
  const int wg = (int)blockIdx.x & 31;
  const void* Gv  = dir ? GB : GA;
  const void* Whh = dir ? WhhB : WhhA;
  u16* Hhi = dir ? Hh1 : Hh0;
  u16* Hlo = dir ? Hl1 : Hl0;
  lstm_body(wg, dir, t0, t1, dir ? s0B : s0A, Gv, Whh, Hhi, Hlo,
            Cb + (size_t)dir * 16384, mp, uid,
            slots + (size_t)dir * 65536, flags, gHalf);
}

// ---------------------------------------------------------------------------
// Phase 4a: topic_weights -> twT[k][t] fp32, bias -> fp32.
// ---------------------------------------------------------------------------
__global__ __launch_bounds__(256) void k_prep(
    const void* __restrict__ tw, const void* __restrict__ tb,
    float* __restrict__ twT, float* __restrict__ biasT, const u32* __restrict__ flags)
{
  const int isBF = (int)flags[0];
  const int idx = blockIdx.x * 256 + threadIdx.x;
  if (idx < 102400) {
    const int t = idx >> 10, k = idx & 1023;
    twT[k * 100 + t] = ldF(tw, idx, isBF);
  } else if (idx < 102500) {
    biasT[idx - 102400] = ldF(tb, idx - 102400, isBF);
  }
}

// ---------------------------------------------------------------------------
// Phase 4: per (b,u): logits(100) -> softmax -> emb row (fp32).
// ---------------------------------------------------------------------------
__global__ __launch_bounds__(256) void k_topic(
    const float* __restrict__ mp, const float* __restrict__ twT,
    const float* __restrict__ biasT, const void* __restrict__ table,
    float* __restrict__ emb, const u32* __restrict__ flags)
{
  const int isBF = (int)flags[0];
  const int bu = blockIdx.x;
  const int tid = threadIdx.x;
  __shared__ float lrow[1024];
  __shared__ float red[128];
  __shared__ float parr[128];
  for (int i = tid; i < 1024; i += 256) lrow[i] = mp[(size_t)bu * 1024 + i];
  __syncthreads();
  float lacc = -1e30f;
  if (tid < 100) {
    lacc = biasT[tid];
    for (int k = 0; k < 1024; ++k) lacc = fmaf(lrow[k], twT[k * 100 + tid], lacc);
  }
  if (tid < 128) red[tid] = (tid < 100) ? lacc : -1e30f;
  __syncthreads();
  for (int off = 64; off > 0; off >>= 1) {
    if (tid < off) red[tid] = fmaxf(red[tid], red[tid + off]);
    __syncthreads();
  }
  const float mxv = red[0];
  __syncthreads();
  const float e = (tid < 100) ? expf(lacc - mxv) : 0.f;
  if (tid < 128) red[tid] = e;
  __syncthreads();
  for (int off = 64; off > 0; off >>= 1) {
    if (tid < off) red[tid] += red[tid + off];
    __syncthreads();
  }
  const float inv = 1.f / red[0];
  if (tid < 128) parr[tid] = e * inv;
  __syncthreads();
#pragma unroll
  for (int r = 0; r < 4; ++r) {
    const int w = tid + 256 * r;
    float a = 0.f;
    for (int t = 0; t < 100; ++t)
      a = fmaf(parr[t], ldF(table, (size_t)t * 1024 + w, isBF), a);
    emb[(size_t)bu * 1024 + w] = a;
  }
}

// ---------------------------------------------------------------------------
// Phase 5: out = emb[b][clip(|uid|-1,0,31)][w] * {1,2,0}. Dtype by flag.
// ---------------------------------------------------------------------------
__global__ __launch_bounds__(256) void k_out(
    const float* __restrict__ emb, const void* __restrict__ uid,
    void* __restrict__ outv, const u32* __restrict__ flags)
{
  const int isBF = (int)flags[0];
  const int is64 = (int)flags[1];
  const int idx = blockIdx.x * 256 + threadIdx.x;
  const int w = idx & 1023;
  const int s = (idx >> 10) & 511;
  const int b = idx >> 19;
  const int id = ldI(uid, b * 512 + s, is64);
  const float wt = (id > 0) ? 1.f : ((id < 0) ? 2.f : 0.f);
  int au = (id < 0) ? (-id - 1) : (id - 1);
  au = max(0, min(31, au));
  const float v = emb[(size_t)(b * 32 + au) * 1024 + w] * wt;
  if (isBF) ((u16*)outv)[idx] = f2bf(v);
  else      ((float*)outv)[idx] = v;
}

// ---------------------------------------------------------------------------
// ws layout (phased fused dirs):
//  fp32-G (ws >= 143,934,464; R5 proved >=176.7MB):
//    GA 64Mi | GB 64Mi | Hh0,Hl0,Hh1,Hl1 4x64Ki | Cb 128Ki | mp 4Mi | emb 4Mi
//    | twT 400Ki | biasT 512 | slots 512Ki (2 dirs x 32 x 4KB) | flags 512
//  fp16-G fallback: GA/GB 32Mi each + same tail ~= 76.8 MB
// ---------------------------------------------------------------------------
extern "C" void kernel_launch(void* const* d_in, const int* in_sizes, int n_in,
                              void* d_out, int out_size, void* d_ws, size_t ws_size,
                              hipStream_t stream) {
  (void)in_sizes; (void)n_in; (void)out_size;
  const void* X    = d_in[0];
  const void* uid  = d_in[1];
  const void* Wihf = d_in[2];
  const void* Whhf = d_in[3];
  const void* bihf = d_in[4];
  const void* bhhf = d_in[5];
  const void* Wihb = d_in[6];
  const void* Whhb = d_in[7];
  const void* bihb = d_in[8];
  const void* bhhb = d_in[9];
  const void* tw   = d_in[10];
  const void* tb   = d_in[11];
  const void* tt   = d_in[12];
  char* ws = (char*)d_ws;

  const int gHalf = (ws_size >= 143934464ull) ? 0 : 1;
  const size_t gB = gHalf ? 33554432ull : 67108864ull;   // per-dir G (256 steps)
  const size_t oGB = gB;
  const size_t oH  = 2ull * gB;
  const size_t oCb = oH + 262144ull;          // 4 slabs x 64Ki
  const size_t omp = oCb + 131072ull;
  const size_t oem = omp + 4194304ull;
  const size_t otw = oem + 4194304ull;
  const size_t obi = otw + 409600ull;
  const size_t osl = obi + 512ull;
  const size_t oFL = osl + 524288ull;

  void*  GA    = (void*)(ws + 0);
  void*  GB    = (void*)(ws + oGB);
  u16*   Hh0   = (u16*)(ws + oH);
  u16*   Hl0   = (u16*)(ws + oH + 65536ull);
  u16*   Hh1   = (u16*)(ws + oH + 131072ull);
  u16*   Hl1   = (u16*)(ws + oH + 196608ull);
  float* Cb    = (float*)(ws + oCb);
  float* mp    = (float*)(ws + omp);
  float* emb   = (float*)(ws + oem);
  float* twT   = (float*)(ws + otw);
  float* biasT = (float*)(ws + obi);
  u32*   slots = (u32*)(ws + osl);
  u32*   flags = (u32*)(ws + oFL);

  (void)hipMemsetAsync(mp, 0, 4194304ull, stream);    // segment-max floor = 0
  (void)hipMemsetAsync(slots, 0, 524288ull, stream);  // barrier slots (spread)
  k_probe<<<1, 256, 0, stream>>>((const u32*)X, (const u32*)uid, flags);

  // Phase A: dir0 s[0,256) -> GA; dir1 s[256,512) -> GB; steps t=0..255.
  k_xproj<<<dim3(128, 32), 256, 0, stream>>>(X, Wihf, bihf, bhhf, GA, flags, gHalf, 0);
  k_xproj<<<dim3(128, 32), 256, 0, stream>>>(X, Wihb, bihb, bhhb, GB, flags, gHalf, 256);
  k_lstm2<<<64, 512, 0, stream>>>(GA, GB, Whhf, Whhb, Hh0, Hl0, Hh1, Hl1,
                                  Cb, mp, uid, slots, flags, gHalf,
                                  0, 256, 0, 256);
  // Phase B: dir0 s[256,512) -> GA; dir1 s[0,256) -> GB; steps t=256..511.
  k_xproj<<<dim3(128, 32), 256, 0, stream>>>(X, Wihf, bihf, bhhf, GA, flags, gHalf, 256);
  k_xproj<<<dim3(128, 32), 256, 0, stream>>>(X, Wihb, bihb, bhhb, GB, flags, gHalf, 0);
  k_lstm2<<<64, 512, 0, stream>>>(GA, GB, Whhf, Whhb, Hh0, Hl0, Hh1, Hl1,
                                  Cb, mp, uid, slots, flags, gHalf,
                                  256, 512, 256, 0);

  k_prep<<<401, 256, 0, stream>>>(tw, tb, twT, biasT, flags);
  k_topic<<<1024, 256, 0, stream>>>(mp, twT, biasT, tt, emb, flags);
  k_out<<<65536, 256, 0, stream>>>(emb, uid, d_out, flags);
}

// Round 12
// 2929.244 us; speedup vs baseline: 2.1498x; 2.1470x over previous
//
#include <hip/hip_runtime.h>
#include <hip/hip_fp16.h>

// GetTopic: biLSTM (B=32,S=512,W=1024,HP=512) -> fused per-utterance segment
// max -> topic softmax (T=100) -> weighted gather. Inputs fp32 (probe kept).
//
// R18 = R15 (4.52 ms, PROVEN; 64 WGs/dir x 256 thr) + ONE delta: the B-frag
// (Whh) setup loop is now fully unrolled. R16/R17 post-mortem (VGPR=52
// invariant to launch_bounds) exposed rule-#20: '#pragma unroll 1' made
// bhi[]/blo[] runtime-indexed -> SCRATCH-allocated in every prior round
// (R15's VGPR=88 proves it) -> 512 B/thread/step scratch re-reads inside
// the MFMA chain. Full unroll -> compile-time indices -> register-resident
// (~+128 VGPR, free: 128 persistent WGs on 256 CUs = <=1 WG/CU).
// The 512-thread geometry (R16/R17, 2674 us vs R15 1810) is REVERTED.
// Everything else verbatim R15: sc1 h exchange + XOR-swizzled LDS slab
// stage, slot barrier (4KB spread), LDS-staged wave0 h stores, MFMA xproj,
// deferred mp atomicMax, phased dual-dir execution.

typedef unsigned short u16;
typedef unsigned int   u32;
typedef unsigned long long u64;
typedef __attribute__((ext_vector_type(8))) short short8;
typedef __attribute__((ext_vector_type(4))) float float4v;

__device__ __forceinline__ float bf2f(u16 u) { return __uint_as_float(((u32)u) << 16); }
__device__ __forceinline__ u16 f2bf(float f) {
  u32 u = __float_as_uint(f);
  u32 r = u + 0x7FFFu + ((u >> 16) & 1u);   // RNE
  return (u16)(r >> 16);
}
__device__ __forceinline__ float sigm(float x) { return 1.f / (1.f + expf(-x)); }

__device__ __forceinline__ float ldF(const void* p, size_t i, int isBF) {
  return isBF ? bf2f(((const u16*)p)[i]) : ((const float*)p)[i];
}
__device__ __forceinline__ int ldI(const void* p, int i, int is64) {
  return is64 ? (int)((const u32*)p)[(size_t)2 * i] : ((const int*)p)[i];
}

union U4S8 { uint4 u; short8 s; u16 us[8]; };

// ---------------------------------------------------------------------------
// Probe: input storage formats from raw bits (R4/R5-proven).
// flags[0]: 1 = float tensors bf16, 0 = fp32.  flags[1]: 1 = ids int64.
// ---------------------------------------------------------------------------
__global__ __launch_bounds__(256) void k_probe(
    const u32* __restrict__ X, const u32* __restrict__ U, u32* __restrict__ flags)
{
  __shared__ int cnt[2];
  if (threadIdx.x == 0) { cnt[0] = 0; cnt[1] = 0; }
  __syncthreads();
  int c0 = 0;
  for (int i = threadIdx.x; i < 1024; i += 256) {
    const u32 e = (X[i] >> 7) & 0xFFu;
    if (e >= 112u && e <= 143u) c0++;
  }
  int c1 = 0;
  {
    const u32 w = U[2 * threadIdx.x + 1];
    if (w == 0u || w == 0xFFFFFFFFu) c1++;
  }
  atomicAdd(&cnt[0], c0);
  atomicAdd(&cnt[1], c1);
  __syncthreads();
  if (threadIdx.x == 0) {
    flags[0] = (cnt[0] >= 512) ? 1u : 0u;
    flags[1] = (cnt[1] >= 128) ? 1u : 0u;
  }
}

// ---------------------------------------------------------------------------
// Phase 1: G_local[sl][n][b] = x[s0+sl] @ Wih^T + (bih+bhh) for sl in [0,256).
// R14-proven: split-bf16 MFMA GEMM. M=8192 (m=sl*32+b), N=2048, K=1024.
// ---------------------------------------------------------------------------
__global__ __launch_bounds__(256) void k_xproj(
    const void* __restrict__ X, const void* __restrict__ Wih,
    const void* __restrict__ bih, const void* __restrict__ bhh,
    void* __restrict__ Gv, const u32* __restrict__ flags, int gHalf, int s0)
{
  const int isBF = (int)flags[0];
  const int m0 = blockIdx.x * 64;
  const int n0 = blockIdx.y * 64;
  __shared__ u16 Ah[64][40];   // stride 40 u16 (80B)
  __shared__ u16 Al[64][40];
  __shared__ u16 Bh[64][40];
  __shared__ u16 Bl[64][40];
  const int tid = threadIdx.x;
  const int lrow = tid >> 2;          // 0..63: staging row
  const int lkg  = (tid & 3) * 8;     // k-group of 8 within 32-wide k-tile
  const int lane = tid & 63;
  const int wid  = tid >> 6;          // wave -> M-chunk
  const int l15  = lane & 15;
  const int quad = lane >> 4;
  const int am = m0 + lrow;
  const int ab = am & 31, asl = am >> 5;           // m = sl*32 + b
  const size_t arow = ((size_t)ab * 512 + (s0 + asl)) * 1024;
  const size_t brow = (size_t)(n0 + lrow) * 1024;

  float4v acc[4];
#pragma unroll
  for (int c = 0; c < 4; ++c) {
    acc[c].x = 0.f; acc[c].y = 0.f; acc[c].z = 0.f; acc[c].w = 0.f;
  }

  for (int k0 = 0; k0 < 1024; k0 += 32) {
    float a8[8], b8[8];
    if (isBF) {
      const u16* Xh = (const u16*)X;
      const u16* Wh = (const u16*)Wih;
      uint4 va = *(const uint4*)(Xh + arow + k0 + lkg);
      uint4 vb = *(const uint4*)(Wh + brow + k0 + lkg);
      const u32 wa[4] = {va.x, va.y, va.z, va.w};
      const u32 wb[4] = {vb.x, vb.y, vb.z, vb.w};
#pragma unroll
      for (int q = 0; q < 4; ++q) {
        a8[2 * q]     = __uint_as_float(wa[q] << 16);
        a8[2 * q + 1] = __uint_as_float(wa[q] & 0xFFFF0000u);
        b8[2 * q]     = __uint_as_float(wb[q] << 16);
        b8[2 * q + 1] = __uint_as_float(wb[q] & 0xFFFF0000u);
      }
    } else {
      const float* Xf = (const float*)X;
      const float* Wf = (const float*)Wih;
      const float4 xa0 = *(const float4*)(Xf + arow + k0 + lkg);
      const float4 xa1 = *(const float4*)(Xf + arow + k0 + lkg + 4);
      const float4 xb0 = *(const float4*)(Wf + brow + k0 + lkg);
      const float4 xb1 = *(const float4*)(Wf + brow + k0 + lkg + 4);
      a8[0] = xa0.x; a8[1] = xa0.y; a8[2] = xa0.z; a8[3] = xa0.w;
      a8[4] = xa1.x; a8[5] = xa1.y; a8[6] = xa1.z; a8[7] = xa1.w;
      b8[0] = xb0.x; b8[1] = xb0.y; b8[2] = xb0.z; b8[3] = xb0.w;
      b8[4] = xb1.x; b8[5] = xb1.y; b8[6] = xb1.z; b8[7] = xb1.w;
    }
    U4S8 pah, pal, pbh, pbl;
#pragma unroll
    for (int j = 0; j < 8; ++j) {
      const u16 ah = f2bf(a8[j]);
      pah.us[j] = ah; pal.us[j] = f2bf(a8[j] - bf2f(ah));
      const u16 bh = f2bf(b8[j]);
      pbh.us[j] = bh; pbl.us[j] = f2bf(b8[j] - bf2f(bh));
    }
    *(uint4*)&Ah[lrow][lkg] = pah.u;
    *(uint4*)&Al[lrow][lkg] = pal.u;
    *(uint4*)&Bh[lrow][lkg] = pbh.u;
    *(uint4*)&Bl[lrow][lkg] = pbl.u;
    __syncthreads();

    U4S8 fah, fal;
    fah.u = *(const uint4*)&Ah[wid * 16 + l15][quad * 8];
    fal.u = *(const uint4*)&Al[wid * 16 + l15][quad * 8];
#pragma unroll
    for (int c = 0; c < 4; ++c) {
      U4S8 fbh, fbl;
      fbh.u = *(const uint4*)&Bh[c * 16 + l15][quad * 8];
      fbl.u = *(const uint4*)&Bl[c * 16 + l15][quad * 8];
      acc[c] = __builtin_amdgcn_mfma_f32_16x16x32_bf16(fah.s, fbh.s, acc[c], 0, 0, 0);
      acc[c] = __builtin_amdgcn_mfma_f32_16x16x32_bf16(fah.s, fbl.s, acc[c], 0, 0, 0);
      acc[c] = __builtin_amdgcn_mfma_f32_16x16x32_bf16(fal.s, fbh.s, acc[c], 0, 0, 0);
    }
    __syncthreads();
  }

  const int mrow = m0 + wid * 16 + quad * 4;
  const int b0 = mrow & 31, sl = mrow >> 5;
#pragma unroll
  for (int c = 0; c < 4; ++c) {
    const int n = n0 + c * 16 + l15;
    const float bias = ldF(bih, n, isBF) + ldF(bhh, n, isBF);
    const size_t off = ((size_t)sl * 2048 + n) * 32 + b0;
    if (gHalf) {
      ushort4 pk;
      pk.x = __half_as_ushort(__float2half(acc[c].x + bias));
      pk.y = __half_as_ushort(__float2half(acc[c].y + bias));
      pk.z = __half_as_ushort(__float2half(acc[c].z + bias));
      pk.w = __half_as_ushort(__float2half(acc[c].w + bias));
      *(uint2*)((u16*)Gv + off) = *(uint2*)&pk;
    } else {
      float4 pk;
      pk.x = acc[c].x + bias; pk.y = acc[c].y + bias;
      pk.z = acc[c].z + bias; pk.w = acc[c].w + bias;
      *(float4*)((float*)Gv + off) = pk;
    }
  }
}

// ---------------------------------------------------------------------------
// Phase 2 body. One dir, 64 WGs x 256. WG owns 8 hidden units = 32 gate
// cols; Whh register-resident as split-bf16 MFMA fragments (R18: setup loop
// fully unrolled -> compile-time indices -> no scratch allocation).
// Prev-step h slabs (64 KB) cooperatively staged into XOR-swizzled LDS.
// ---------------------------------------------------------------------------
__device__ __forceinline__ void lstm_body(
    const int wg, const int dir, const int t0, const int t1, const int s0,
    const void* __restrict__ Gv, const void* __restrict__ Whh,
    u16* __restrict__ Hhi, u16* __restrict__ Hlo, float* __restrict__ Cb,
    float* __restrict__ mp, const void* __restrict__ uid,
    u32* __restrict__ slots, const u32* __restrict__ flags, const int gHalf)
{
  __shared__ float gl[1024];                    // [col32][b32] gate preacts
  __shared__ __align__(16) u16 shh[256];        // staged h hi: [b32][u8]
  __shared__ __align__(16) u16 shl[256];        // staged h lo: [b32][u8]
  __shared__ __align__(16) u16 HhS[16384];      // 32 KB swizzled h-hi slab
  __shared__ __align__(16) u16 HlS[16384];      // 32 KB swizzled h-lo slab
  const int isBF = (int)flags[0];
  const int is64 = (int)flags[1];
  const int tid = threadIdx.x;
  const int j0 = wg * 8;
  const int lane = tid & 63;
  const int wid = tid >> 6;
  const int mt = wid & 1, nt = wid >> 1;
  const int l15 = lane & 15;
  const int quad = lane >> 4;
  const int nl = nt * 16 + l15;        // col 0..31 within WG
  const int n = ((nl >> 3) * 512) + j0 + (nl & 7);   // global gate row/col

  // B-frags: split-bf16 of Whh row n. B[n=l15][k=quad*8+j].
  // R18: FULL unroll -> bhi/blo are SSA register values, not scratch.
  short8 bhi[16], blo[16];
#pragma unroll
  for (int kt = 0; kt < 16; ++kt) {
    const int k0 = kt * 32 + quad * 8;
    float w[8];
    if (isBF) {
      const u16* Wh = (const u16*)Whh;
#pragma unroll
      for (int jj = 0; jj < 8; ++jj) w[jj] = bf2f(Wh[(size_t)n * 512 + k0 + jj]);
    } else {
      const float* Wf = (const float*)Whh;
      const float4 w0 = *(const float4*)(Wf + (size_t)n * 512 + k0);
      const float4 w1 = *(const float4*)(Wf + (size_t)n * 512 + k0 + 4);
      w[0] = w0.x; w[1] = w0.y; w[2] = w0.z; w[3] = w0.w;
      w[4] = w1.x; w[5] = w1.y; w[6] = w1.z; w[7] = w1.w;
    }
    U4S8 ph, pl;
#pragma unroll
    for (int jj = 0; jj < 8; ++jj) {
      const u16 hi = f2bf(w[jj]);
      const float rem = w[jj] - bf2f(hi);   // exact (Sterbenz)
      ph.us[jj] = hi; pl.us[jj] = f2bf(rem);
    }
    bhi[kt] = ph.s; blo[kt] = pl.s;
  }

  const int b_a = mt * 16 + l15;        // A row = batch
  const int cb = tid & 31;              // consumer: batch
  const int ciu = tid >> 5;             // consumer: unit 0..7
  float c = (t0 == 0) ? 0.f : Cb[cb * 512 + j0 + ciu];

  // Per-thread G column offset; per-step local offset = ls*65536 + gcol.
  const size_t gcol = (size_t)n * 32 + (size_t)(mt * 16 + quad * 4);

  // Prefetch G for t=t0 (plain cached loads -- L2 stays warm).
  float4v gpre;
  {
    const int ls = dir ? (511 - t0 - s0) : (t0 - s0);
    const size_t goff = (size_t)ls * 65536 + gcol;
    if (gHalf) {
      const __half* Gp = (const __half*)Gv;
      gpre.x = __half2float(Gp[goff + 0]);
      gpre.y = __half2float(Gp[goff + 1]);
      gpre.z = __half2float(Gp[goff + 2]);
      gpre.w = __half2float(Gp[goff + 3]);
    } else {
      const float4 gv = *(const float4*)((const float*)Gv + goff);
      gpre.x = gv.x; gpre.y = gv.y; gpre.z = gv.z; gpre.w = gv.w;
    }
  }

  // A-fragment LDS byte offset (swizzled): row b_a, col byte kt*64+quad*16.
  const int abase_sw = b_a * 1024;
  const int aswz = (b_a & 7) << 4;

  for (int t = t0; t < t1; ++t) {
    const int sidx = dir ? (511 - t) : t;
    if (t > t0) {
      // Parallel detection: lane i of wave 0 polls slot i (4KB spread).
      if (tid < 64) {
        const u32 target = (u32)t;
        const u32* sl = slots + (size_t)lane * 1024;   // 4KB stride
        for (;;) {
          const u32 v = __hip_atomic_load(sl, __ATOMIC_RELAXED, __HIP_MEMORY_SCOPE_AGENT);
          if (__all((int)(v >= target))) break;
          __builtin_amdgcn_s_sleep(1);
        }
      }
      __syncthreads();
    }

    // C-init from prefetched G (4 consecutive batches per lane, col n).
    float4v acc_hh = gpre;
    float4v acc_hl, acc_lh;
    acc_hl.x = 0.f; acc_hl.y = 0.f; acc_hl.z = 0.f; acc_hl.w = 0.f;
    acc_lh.x = 0.f; acc_lh.y = 0.f; acc_lh.z = 0.f; acc_lh.w = 0.f;

    if (t > 0) {
      // Cooperative coalesced stage of prev-step h slabs into LDS.
      // Thread loads bytes [tid*16 + j*4096) of each 32 KB slab (16B/lane
      // contiguous runs), sc1 (MALL-coherent); writes LDS with the read
      // swizzle byte ^= ((row&7)<<4), row = byte>>10.
      const u16* sbh = Hhi + (size_t)((t - 1) & 1) * 16384;
      const u16* sbl = Hlo + (size_t)((t - 1) & 1) * 16384;
      uint4 th[8], tl[8];
#pragma unroll
      for (int j = 0; j < 8; ++j) {
        const u16* ph = sbh + tid * 8 + j * 2048;
        const u16* pl = sbl + tid * 8 + j * 2048;
        asm volatile(
            "global_load_dwordx4 %0, %2, off sc1\n\t"
            "global_load_dwordx4 %1, %3, off sc1"
            : "=v"(th[j]), "=v"(tl[j])
            : "v"(ph), "v"(pl)
            : "memory");
      }
      asm volatile("s_waitcnt vmcnt(0)" ::: "memory");
      __builtin_amdgcn_sched_barrier(0);
#pragma unroll
      for (int j = 0; j < 8; ++j) {
        const int L = tid * 16 + j * 4096;
        const int a = L ^ (((L >> 10) & 7) << 4);
        *(uint4*)((char*)HhS + a) = th[j];
        *(uint4*)((char*)HlS + a) = tl[j];
      }
      __syncthreads();

#pragma unroll
      for (int kt = 0; kt < 16; ++kt) {
        const int aoff = (abase_sw + kt * 64 + quad * 16) ^ aswz;
        U4S8 va, vl;
        va.u = *(const uint4*)((const char*)HhS + aoff);
        vl.u = *(const uint4*)((const char*)HlS + aoff);
        acc_hh = __builtin_amdgcn_mfma_f32_16x16x32_bf16(va.s, bhi[kt], acc_hh, 0, 0, 0);
        acc_hl = __builtin_amdgcn_mfma_f32_16x16x32_bf16(va.s, blo[kt], acc_hl, 0, 0, 0);
        acc_lh = __builtin_amdgcn_mfma_f32_16x16x32_bf16(vl.s, bhi[kt], acc_lh, 0, 0, 0);
      }
    }

    // Prefetch next step's G (independent; hides under exchange + barrier).
    if (t + 1 < t1) {
      const int ls = dir ? (511 - (t + 1) - s0) : (t + 1 - s0);
      const size_t goff = (size_t)ls * 65536 + gcol;
      if (gHalf) {
        const __half* Gp = (const __half*)Gv;
        gpre.x = __half2float(Gp[goff + 0]);
        gpre.y = __half2float(Gp[goff + 1]);
        gpre.z = __half2float(Gp[goff + 2]);
        gpre.w = __half2float(Gp[goff + 3]);
      } else {
        const float4 gv = *(const float4*)((const float*)Gv + goff);
        gpre.x = gv.x; gpre.y = gv.y; gpre.z = gv.z; gpre.w = gv.w;
      }
    }

    // exchange: D row (quad*4+r) = batch - mt*16, col l15 -> nl
    {
      const int base = nl * 32 + mt * 16 + quad * 4;
      gl[base + 0] = acc_hh.x + acc_hl.x + acc_lh.x;
      gl[base + 1] = acc_hh.y + acc_hl.y + acc_lh.y;
      gl[base + 2] = acc_hh.z + acc_hl.z + acc_lh.z;
      gl[base + 3] = acc_hh.w + acc_hl.w + acc_lh.w;
    }
    __syncthreads();

    float hval;
    int id;
    {
      const float a0 = gl[(0 * 8 + ciu) * 32 + cb];
      const float a1 = gl[(1 * 8 + ciu) * 32 + cb];
      const float a2 = gl[(2 * 8 + ciu) * 32 + cb];
      const float a3 = gl[(3 * 8 + ciu) * 32 + cb];
      const float ig = sigm(a0), fg = sigm(a1);
      const float gg = tanhf(a2), og = sigm(a3);
      c = fg * c + ig * gg;
      hval = og * tanhf(c);
      const u16 hh = f2bf(hval);
      shh[cb * 8 + ciu] = hh;
      shl[cb * 8 + ciu] = f2bf(hval - bf2f(hh));
      id = ldI(uid, cb * 512 + sidx, is64);
    }
    __syncthreads();

    // Wave 0: re-gather staged h, 128x 8B agent stores (16B runs per batch),
    // one drain, tid0 publishes. Other waves proceed to atomicMax.
    if (tid < 64) {
      const int sb = lane >> 1, q = lane & 1;       // batch, 4-unit chunk
      const u64 vh = ((const u64*)shh)[sb * 2 + q];
      const u64 vo = ((const u64*)shl)[sb * 2 + q];
      const size_t so = (size_t)(t & 1) * 16384 + (size_t)sb * 512 + j0 + q * 4;
      __hip_atomic_store((u64*)(Hhi + so), vh, __ATOMIC_RELAXED, __HIP_MEMORY_SCOPE_AGENT);
      __hip_atomic_store((u64*)(Hlo + so), vo, __ATOMIC_RELAXED, __HIP_MEMORY_SCOPE_AGENT);
      asm volatile("s_waitcnt vmcnt(0)" ::: "memory");
      if (tid == 0)
        __hip_atomic_store(slots + (size_t)wg * 1024, (u32)(t + 1),
                           __ATOMIC_RELAXED, __HIP_MEMORY_SCOPE_AGENT);
    }
    // Deferred fused max-pool: overlaps the next poll.
    if (id > 0 && hval > 0.f)
      atomicMax((int*)&mp[(size_t)(cb * 32 + (id - 1)) * 1024 + dir * 512 + (j0 + ciu)],
                __float_as_int(hval));
  }

  if (t1 < 512) Cb[cb * 512 + j0 + ciu] = c;   // spill c across phase boundary
}

// Fused dual-direction phase kernel: WGs 0..63 = dir0, 64..127 = dir1.
__global__ __launch_bounds__(256) void k_lstm2(
    const void* __restrict__ GA, const void* __restrict__ GB,
    const void* __restrict__ WhhA, const void* __restrict__ WhhB,
    u16* __restrict__ Hh0, u16* __restrict__ Hl0,
    u16* __restrict__ Hh1, u16* __restrict__ Hl1,
    float* __restrict__ Cb, float* __restrict__ mp,
    const void* __restrict__ uid, u32* __restrict__ slots,
    const u32* __restrict__ flags, int gHalf,
    int t0, int t1, int s0A, int s0B)
{
  const int dir = ((int)blockIdx.x >= 64) ? 1 : 0;
  const int wg = (int)blockIdx.x & 63;
  const void* Gv  = dir ? GB : GA;
  const void* Whh = dir ? WhhB : WhhA;
  u16* Hhi = dir ? Hh1 : Hh0;
  u16* Hlo = dir ? Hl1 : Hl0;
  lstm_body(wg, dir, t0, t1, dir ? s0B : s0A, Gv, Whh, Hhi, Hlo,
            Cb + (size_t)dir * 16384, mp, uid,
            slots + (size_t)dir * 65536, flags, gHalf);
}

// ---------------------------------------------------------------------------
// Phase 4a: topic_weights -> twT[k][t] fp32, bias -> fp32.
// ---------------------------------------------------------------------------
__global__ __launch_bounds__(256) void k_prep(
    const void* __restrict__ tw, const void* __restrict__ tb,
    float* __restrict__ twT, float* __restrict__ biasT, const u32* __restrict__ flags)
{
  const int isBF = (int)flags[0];
  const int idx = blockIdx.x * 256 + threadIdx.x;
  if (idx < 102400) {
    const int t = idx >> 10, k = idx & 1023;
    twT[k * 100 + t] = ldF(tw, idx, isBF);
  } else if (idx < 102500) {
    biasT[idx - 102400] = ldF(tb, idx - 102400, isBF);
  }
}

// ---------------------------------------------------------------------------
// Phase 4: per (b,u): logits(100) -> softmax -> emb row (fp32).
// ---------------------------------------------------------------------------
__global__ __launch_bounds__(256) void k_topic(
    const float* __restrict__ mp, const float* __restrict__ twT,
    const float* __restrict__ biasT, const void* __restrict__ table,
    float* __restrict__ emb, const u32* __restrict__ flags)
{
  const int isBF = (int)flags[0];
  const int bu = blockIdx.x;
  const int tid = threadIdx.x;
  __shared__ float lrow[1024];
  __shared__ float red[128];
  __shared__ float parr[128];
  for (int i = tid; i < 1024; i += 256) lrow[i] = mp[(size_t)bu * 1024 + i];
  __syncthreads();
  float lacc = -1e30f;
  if (tid < 100) {
    lacc = biasT[tid];
    for (int k = 0; k < 1024; ++k) lacc = fmaf(lrow[k], twT[k * 100 + tid], lacc);
  }
  if (tid < 128) red[tid] = (tid < 100) ? lacc : -1e30f;
  __syncthreads();
  for (int off = 64; off > 0; off >>= 1) {
    if (tid < off) red[tid] = fmaxf(red[tid], red[tid + off]);
    __syncthreads();
  }
  const float mxv = red[0];
  __syncthreads();
  const float e = (tid < 100) ? expf(lacc - mxv) : 0.f;
  if (tid < 128) red[tid] = e;
  __syncthreads();
  for (int off = 64; off > 0; off >>= 1) {
    if (tid < off) red[tid] += red[tid + off];
    __syncthreads();
  }
  const float inv = 1.f / red[0];
  if (tid < 128) parr[tid] = e * inv;
  __syncthreads();
#pragma unroll
  for (int r = 0; r < 4; ++r) {
    const int w = tid + 256 * r;
    float a = 0.f;
    for (int t = 0; t < 100; ++t)
      a = fmaf(parr[t], ldF(table, (size_t)t * 1024 + w, isBF), a);
    emb[(size_t)bu * 1024 + w] = a;
  }
}

// ---------------------------------------------------------------------------
// Phase 5: out = emb[b][clip(|uid|-1,0,31)][w] * {1,2,0}. Dtype by flag.
// ---------------------------------------------------------------------------
__global__ __launch_bounds__(256) void k_out(
    const float* __restrict__ emb, const void* __restrict__ uid,
    void* __restrict__ outv, const u32* __restrict__ flags)
{
  const int isBF = (int)flags[0];
  const int is64 = (int)flags[1];
  const int idx = blockIdx.x * 256 + threadIdx.x;
  const int w = idx & 1023;
  const int s = (idx >> 10) & 511;
  const int b = idx >> 19;
  const int id = ldI(uid, b * 512 + s, is64);
  const float wt = (id > 0) ? 1.f : ((id < 0) ? 2.f : 0.f);
  int au = (id < 0) ? (-id - 1) : (id - 1);
  au = max(0, min(31, au));
  const float v = emb[(size_t)(b * 32 + au) * 1024 + w] * wt;
  if (isBF) ((u16*)outv)[idx] = f2bf(v);
  else      ((float*)outv)[idx] = v;
}

// ---------------------------------------------------------------------------
// ws layout (phased fused dirs):
//  fp32-G (ws >= 143,934,464; R5 proved >=176.7MB):
//    GA 64Mi | GB 64Mi | Hh0,Hl0,Hh1,Hl1 4x64Ki | Cb 128Ki | mp 4Mi | emb 4Mi
//    | twT 400Ki | biasT 512 | slots 512Ki (128 x 4KB spread) | flags 512
//  fp16-G fallback: GA/GB 32Mi each + same tail ~= 76.8 MB
// ---------------------------------------------------------------------------
extern "C" void kernel_launch(void* const* d_in, const int* in_sizes, int n_in,
                              void* d_out, int out_size, void* d_ws, size_t ws_size,
                              hipStream_t stream) {
  (void)in_sizes; (void)n_in; (void)out_size;
  const void* X    = d_in[0];
  const void* uid  = d_in[1];
  const void* Wihf = d_in[2];
  const void* Whhf = d_in[3];
  const void* bihf = d_in[4];
  const void* bhhf = d_in[5];
  const void* Wihb = d_in[6];
  const void* Whhb = d_in[7];
  const void* bihb = d_in[8];
  const void* bhhb = d_in[9];
  const void* tw   = d_in[10];
  const void* tb   = d_in[11];
  const void* tt   = d_in[12];
  char* ws = (char*)d_ws;

  const int gHalf = (ws_size >= 143934464ull) ? 0 : 1;
  const size_t gB = gHalf ? 33554432ull : 67108864ull;   // per-dir G (256 steps)
  const size_t oGB = gB;
  const size_t oH  = 2ull * gB;
  const size_t oCb = oH + 262144ull;          // 4 slabs x 64Ki
  const size_t omp = oCb + 131072ull;
  const size_t oem = omp + 4194304ull;
  const size_t otw = oem + 4194304ull;
  const size_t obi = otw + 409600ull;
  const size_t osl = obi + 512ull;
  const size_t oFL = osl + 524288ull;

  void*  GA    = (void*)(ws + 0);
  void*  GB    = (void*)(ws + oGB);
  u16*   Hh0   = (u16*)(ws + oH);
  u16*   Hl0   = (u16*)(ws + oH + 65536ull);
  u16*   Hh1   = (u16*)(ws + oH + 131072ull);
  u16*   Hl1   = (u16*)(ws + oH + 196608ull);
  float* Cb    = (float*)(ws + oCb);
  float* mp    = (float*)(ws + omp);
  float* emb   = (float*)(ws + oem);
  float* twT   = (float*)(ws + otw);
  float* biasT = (float*)(ws + obi);
  u32*   slots = (u32*)(ws + osl);
  u32*   flags = (u32*)(ws + oFL);

  (void)hipMemsetAsync(mp, 0, 4194304ull, stream);    // segment-max floor = 0
  (void)hipMemsetAsync(slots, 0, 524288ull, stream);  // barrier slots (spread)
  k_probe<<<1, 256, 0, stream>>>((const u32*)X, (const u32*)uid, flags);

  // Phase A: dir0 s[0,256) -> GA; dir1 s[256,512) -> GB; steps t=0..255.
  k_xproj<<<dim3(128, 32), 256, 0, stream>>>(X, Wihf, bihf, bhhf, GA, flags, gHalf, 0);
  k_xproj<<<dim3(128, 32), 256, 0, stream>>>(X, Wihb, bihb, bhhb, GB, flags, gHalf, 256);
  k_lstm2<<<128, 256, 0, stream>>>(GA, GB, Whhf, Whhb, Hh0, Hl0, Hh1, Hl1,
                                   Cb, mp, uid, slots, flags, gHalf,
                                   0, 256, 0, 256);
  // Phase B: dir0 s[256,512) -> GA; dir1 s[0,256) -> GB; steps t=256..511.
  k_xproj<<<dim3(128, 32), 256, 0, stream>>>(X, Wihf, bihf, bhhf, GA, flags, gHalf, 256);
  k_xproj<<<dim3(128, 32), 256, 0, stream>>>(X, Wihb, bihb, bhhb, GB, flags, gHalf, 0);
  k_lstm2<<<128, 256, 0, stream>>>(GA, GB, Whhf, Whhb, Hh0, Hl0, Hh1, Hl1,
                                   Cb, mp, uid, slots, flags, gHalf,
                                   256, 512, 256, 0);

  k_prep<<<401, 256, 0, stream>>>(tw, tb, twT, biasT, flags);
  k_topic<<<1024, 256, 0, stream>>>(mp, twT, biasT, tt, emb, flags);
  k_out<<<65536, 256, 0, stream>>>(emb, uid, d_out, flags);
}

// Round 14
// 2923.283 us; speedup vs baseline: 2.1542x; 1.0020x over previous
//
#include <hip/hip_runtime.h>
#include <hip/hip_fp16.h>

// GetTopic: biLSTM (B=32,S=512,W=1024,HP=512) -> fused per-utterance segment
// max -> topic softmax (T=100) -> weighted gather. Inputs fp32 (probe kept).
//
// R20 = R18 VERBATIM (2.93 ms, PROVEN incl. graph-replay checks).
// R19 (32 WGs/dir x 512 thr) diverged intermittently on timed replays
// (absmax 9.19 post-timing): the 512-thread geometry has a timing-dependent
// race that only opens at ~3 us/step (R16/R17 masked it by running 10.5
// us/step due to the scratch bug). Mechanism not identified analytically ->
// per discipline, revert to the proven kernel rather than guess-fix a race.
//
// R18's content: R15 structure (64 WGs/dir x 256 thr; sc1 h exchange +
// XOR-swizzled LDS slab stage; 4KB-spread slot barrier; LDS-staged wave0 h
// stores; MFMA split-bf16 xproj; deferred mp atomicMax; phased dual-dir
// k_lstm2) + the rule-#20 fix: Whh B-frag setup loop FULLY unrolled so
// bhi[]/blo[] are SSA register values (VGPR 148), not scratch.

typedef unsigned short u16;
typedef unsigned int   u32;
typedef unsigned long long u64;
typedef __attribute__((ext_vector_type(8))) short short8;
typedef __attribute__((ext_vector_type(4))) float float4v;

__device__ __forceinline__ float bf2f(u16 u) { return __uint_as_float(((u32)u) << 16); }
__device__ __forceinline__ u16 f2bf(float f) {
  u32 u = __float_as_uint(f);
  u32 r = u + 0x7FFFu + ((u >> 16) & 1u);   // RNE
  return (u16)(r >> 16);
}
__device__ __forceinline__ float sigm(float x) { return 1.f / (1.f + expf(-x)); }

__device__ __forceinline__ float ldF(const void* p, size_t i, int isBF) {
  return isBF ? bf2f(((const u16*)p)[i]) : ((const float*)p)[i];
}
__device__ __forceinline__ int ldI(const void* p, int i, int is64) {
  return is64 ? (int)((const u32*)p)[(size_t)2 * i] : ((const int*)p)[i];
}

union U4S8 { uint4 u; short8 s; u16 us[8]; };

// ---------------------------------------------------------------------------
// Probe: input storage formats from raw bits (R4/R5-proven).
// flags[0]: 1 = float tensors bf16, 0 = fp32.  flags[1]: 1 = ids int64.
// ---------------------------------------------------------------------------
__global__ __launch_bounds__(256) void k_probe(
    const u32* __restrict__ X, const u32* __restrict__ U, u32* __restrict__ flags)
{
  __shared__ int cnt[2];
  if (threadIdx.x == 0) { cnt[0] = 0; cnt[1] = 0; }
  __syncthreads();
  int c0 = 0;
  for (int i = threadIdx.x; i < 1024; i += 256) {
    const u32 e = (X[i] >> 7) & 0xFFu;
    if (e >= 112u && e <= 143u) c0++;
  }
  int c1 = 0;
  {
    const u32 w = U[2 * threadIdx.x + 1];
    if (w == 0u || w == 0xFFFFFFFFu) c1++;
  }
  atomicAdd(&cnt[0], c0);
  atomicAdd(&cnt[1], c1);
  __syncthreads();
  if (threadIdx.x == 0) {
    flags[0] = (cnt[0] >= 512) ? 1u : 0u;
    flags[1] = (cnt[1] >= 128) ? 1u : 0u;
  }
}

// ---------------------------------------------------------------------------
// Phase 1: G_local[sl][n][b] = x[s0+sl] @ Wih^T + (bih+bhh) for sl in [0,256).
// R14-proven: split-bf16 MFMA GEMM. M=8192 (m=sl*32+b), N=2048, K=1024.
// ---------------------------------------------------------------------------
__global__ __launch_bounds__(256) void k_xproj(
    const void* __restrict__ X, const void* __restrict__ Wih,
    const void* __restrict__ bih, const void* __restrict__ bhh,
    void* __restrict__ Gv, const u32* __restrict__ flags, int gHalf, int s0)
{
  const int isBF = (int)flags[0];
  const int m0 = blockIdx.x * 64;
  const int n0 = blockIdx.y * 64;
  __shared__ u16 Ah[64][40];   // stride 40 u16 (80B)
  __shared__ u16 Al[64][40];
  __shared__ u16 Bh[64][40];
  __shared__ u16 Bl[64][40];
  const int tid = threadIdx.x;
  const int lrow = tid >> 2;          // 0..63: staging row
  const int lkg  = (tid & 3) * 8;     // k-group of 8 within 32-wide k-tile
  const int lane = tid & 63;
  const int wid  = tid >> 6;          // wave -> M-chunk
  const int l15  = lane & 15;
  const int quad = lane >> 4;
  const int am = m0 + lrow;
  const int ab = am & 31, asl = am >> 5;           // m = sl*32 + b
  const size_t arow = ((size_t)ab * 512 + (s0 + asl)) * 1024;
  const size_t brow = (size_t)(n0 + lrow) * 1024;

  float4v acc[4];
#pragma unroll
  for (int c = 0; c < 4; ++c) {
    acc[c].x = 0.f; acc[c].y = 0.f; acc[c].z = 0.f; acc[c].w = 0.f;
  }

  for (int k0 = 0; k0 < 1024; k0 += 32) {
    float a8[8], b8[8];
    if (isBF) {
      const u16* Xh = (const u16*)X;
      const u16* Wh = (const u16*)Wih;
      uint4 va = *(const uint4*)(Xh + arow + k0 + lkg);
      uint4 vb = *(const uint4*)(Wh + brow + k0 + lkg);
      const u32 wa[4] = {va.x, va.y, va.z, va.w};
      const u32 wb[4] = {vb.x, vb.y, vb.z, vb.w};
#pragma unroll
      for (int q = 0; q < 4; ++q) {
        a8[2 * q]     = __uint_as_float(wa[q] << 16);
        a8[2 * q + 1] = __uint_as_float(wa[q] & 0xFFFF0000u);
        b8[2 * q]     = __uint_as_float(wb[q] << 16);
        b8[2 * q + 1] = __uint_as_float(wb[q] & 0xFFFF0000u);
      }
    } else {
      const float* Xf = (const float*)X;
      const float* Wf = (const float*)Wih;
      const float4 xa0 = *(const float4*)(Xf + arow + k0 + lkg);
      const float4 xa1 = *(const float4*)(Xf + arow + k0 + lkg + 4);
      const float4 xb0 = *(const float4*)(Wf + brow + k0 + lkg);
      const float4 xb1 = *(const float4*)(Wf + brow + k0 + lkg + 4);
      a8[0] = xa0.x; a8[1] = xa0.y; a8[2] = xa0.z; a8[3] = xa0.w;
      a8[4] = xa1.x; a8[5] = xa1.y; a8[6] = xa1.z; a8[7] = xa1.w;
      b8[0] = xb0.x; b8[1] = xb0.y; b8[2] = xb0.z; b8[3] = xb0.w;
      b8[4] = xb1.x; b8[5] = xb1.y; b8[6] = xb1.z; b8[7] = xb1.w;
    }
    U4S8 pah, pal, pbh, pbl;
#pragma unroll
    for (int j = 0; j < 8; ++j) {
      const u16 ah = f2bf(a8[j]);
      pah.us[j] = ah; pal.us[j] = f2bf(a8[j] - bf2f(ah));
      const u16 bh = f2bf(b8[j]);
      pbh.us[j] = bh; pbl.us[j] = f2bf(b8[j] - bf2f(bh));
    }
    *(uint4*)&Ah[lrow][lkg] = pah.u;
    *(uint4*)&Al[lrow][lkg] = pal.u;
    *(uint4*)&Bh[lrow][lkg] = pbh.u;
    *(uint4*)&Bl[lrow][lkg] = pbl.u;
    __syncthreads();

    U4S8 fah, fal;
    fah.u = *(const uint4*)&Ah[wid * 16 + l15][quad * 8];
    fal.u = *(const uint4*)&Al[wid * 16 + l15][quad * 8];
#pragma unroll
    for (int c = 0; c < 4; ++c) {
      U4S8 fbh, fbl;
      fbh.u = *(const uint4*)&Bh[c * 16 + l15][quad * 8];
      fbl.u = *(const uint4*)&Bl[c * 16 + l15][quad * 8];
      acc[c] = __builtin_amdgcn_mfma_f32_16x16x32_bf16(fah.s, fbh.s, acc[c], 0, 0, 0);
      acc[c] = __builtin_amdgcn_mfma_f32_16x16x32_bf16(fah.s, fbl.s, acc[c], 0, 0, 0);
      acc[c] = __builtin_amdgcn_mfma_f32_16x16x32_bf16(fal.s, fbh.s, acc[c], 0, 0, 0);
    }
    __syncthreads();
  }

  const int mrow = m0 + wid * 16 + quad * 4;
  const int b0 = mrow & 31, sl = mrow >> 5;
#pragma unroll
  for (int c = 0; c < 4; ++c) {
    const int n = n0 + c * 16 + l15;
    const float bias = ldF(bih, n, isBF) + ldF(bhh, n, isBF);
    const size_t off = ((size_t)sl * 2048 + n) * 32 + b0;
    if (gHalf) {
      ushort4 pk;
      pk.x = __half_as_ushort(__float2half(acc[c].x + bias));
      pk.y = __half_as_ushort(__float2half(acc[c].y + bias));
      pk.z = __half_as_ushort(__float2half(acc[c].z + bias));
      pk.w = __half_as_ushort(__float2half(acc[c].w + bias));
      *(uint2*)((u16*)Gv + off) = *(uint2*)&pk;
    } else {
      float4 pk;
      pk.x = acc[c].x + bias; pk.y = acc[c].y + bias;
      pk.z = acc[c].z + bias; pk.w = acc[c].w + bias;
      *(float4*)((float*)Gv + off) = pk;
    }
  }
}

// ---------------------------------------------------------------------------
// Phase 2 body. One dir, 64 WGs x 256. WG owns 8 hidden units = 32 gate
// cols; Whh register-resident as split-bf16 MFMA fragments (setup loop
// fully unrolled -> compile-time indices -> no scratch allocation).
// Prev-step h slabs (64 KB) cooperatively staged into XOR-swizzled LDS.
// ---------------------------------------------------------------------------
__device__ __forceinline__ void lstm_body(
    const int wg, const int dir, const int t0, const int t1, const int s0,
    const void* __restrict__ Gv, const void* __restrict__ Whh,
    u16* __restrict__ Hhi, u16* __restrict__ Hlo, float* __restrict__ Cb,
    float* __restrict__ mp, const void* __restrict__ uid,
    u32* __restrict__ slots, const u32* __restrict__ flags, const int gHalf)
{
  __shared__ float gl[1024];                    // [col32][b32] gate preacts
  __shared__ __align__(16) u16 shh[256];        // staged h hi: [b32][u8]
  __shared__ __align__(16) u16 shl[256];        // staged h lo: [b32][u8]
  __shared__ __align__(16) u16 HhS[16384];      // 32 KB swizzled h-hi slab
  __shared__ __align__(16) u16 HlS[16384];      // 32 KB swizzled h-lo slab
  const int isBF = (int)flags[0];
  const int is64 = (int)flags[1];
  const int tid = threadIdx.x;
  const int j0 = wg * 8;
  const int lane = tid & 63;
  const int wid = tid >> 6;
  const int mt = wid & 1, nt = wid >> 1;
  const int l15 = lane & 15;
  const int quad = lane >> 4;
  const int nl = nt * 16 + l15;        // col 0..31 within WG
  const int n = ((nl >> 3) * 512) + j0 + (nl & 7);   // global gate row/col

  // B-frags: split-bf16 of Whh row n. B[n=l15][k=quad*8+j].
  // FULL unroll -> bhi/blo are SSA register values, not scratch (rule #20).
  short8 bhi[16], blo[16];
#pragma unroll
  for (int kt = 0; kt < 16; ++kt) {
    const int k0 = kt * 32 + quad * 8;
    float w[8];
    if (isBF) {
      const u16* Wh = (const u16*)Whh;
#pragma unroll
      for (int jj = 0; jj < 8; ++jj) w[jj] = bf2f(Wh[(size_t)n * 512 + k0 + jj]);
    } else {
      const float* Wf = (const float*)Whh;
      const float4 w0 = *(const float4*)(Wf + (size_t)n * 512 + k0);
      const float4 w1 = *(const float4*)(Wf + (size_t)n * 512 + k0 + 4);
      w[0] = w0.x; w[1] = w0.y; w[2] = w0.z; w[3] = w0.w;
      w[4] = w1.x; w[5] = w1.y; w[6] = w1.z; w[7] = w1.w;
    }
    U4S8 ph, pl;
#pragma unroll
    for (int jj = 0; jj < 8; ++jj) {
      const u16 hi = f2bf(w[jj]);
      const float rem = w[jj] - bf2f(hi);   // exact (Sterbenz)
      ph.us[jj] = hi; pl.us[jj] = f2bf(rem);
    }
    bhi[kt] = ph.s; blo[kt] = pl.s;
  }

  const int b_a = mt * 16 + l15;        // A row = batch
  const int cb = tid & 31;              // consumer: batch
  const int ciu = tid >> 5;             // consumer: unit 0..7
  float c = (t0 == 0) ? 0.f : Cb[cb * 512 + j0 + ciu];

  // Per-thread G column offset; per-step local offset = ls*65536 + gcol.
  const size_t gcol = (size_t)n * 32 + (size_t)(mt * 16 + quad * 4);

  // Prefetch G for t=t0 (plain cached loads -- L2 stays warm).
  float4v gpre;
  {
    const int ls = dir ? (511 - t0 - s0) : (t0 - s0);
    const size_t goff = (size_t)ls * 65536 + gcol;
    if (gHalf) {
      const __half* Gp = (const __half*)Gv;
      gpre.x = __half2float(Gp[goff + 0]);
      gpre.y = __half2float(Gp[goff + 1]);
      gpre.z = __half2float(Gp[goff + 2]);
      gpre.w = __half2float(Gp[goff + 3]);
    } else {
      const float4 gv = *(const float4*)((const float*)Gv + goff);
      gpre.x = gv.x; gpre.y = gv.y; gpre.z = gv.z; gpre.w = gv.w;
    }
  }

  // A-fragment LDS byte offset (swizzled): row b_a, col byte kt*64+quad*16.
  const int abase_sw = b_a * 1024;
  const int aswz = (b_a & 7) << 4;

  for (int t = t0; t < t1; ++t) {
    const int sidx = dir ? (511 - t) : t;
    if (t > t0) {
      // Parallel detection: lane i of wave 0 polls slot i (4KB spread).
      if (tid < 64) {
        const u32 target = (u32)t;
        const u32* sl = slots + (size_t)lane * 1024;   // 4KB stride
        for (;;) {
          const u32 v = __hip_atomic_load(sl, __ATOMIC_RELAXED, __HIP_MEMORY_SCOPE_AGENT);
          if (__all((int)(v >= target))) break;
          __builtin_amdgcn_s_sleep(1);
        }
      }
      __syncthreads();
    }

    // C-init from prefetched G (4 consecutive batches per lane, col n).
    float4v acc_hh = gpre;
    float4v acc_hl, acc_lh;
    acc_hl.x = 0.f; acc_hl.y = 0.f; acc_hl.z = 0.f; acc_hl.w = 0.f;
    acc_lh.x = 0.f; acc_lh.y = 0.f; acc_lh.z = 0.f; acc_lh.w = 0.f;

    if (t > 0) {
      // Cooperative coalesced stage of prev-step h slabs into LDS.
      // Thread loads bytes [tid*16 + j*4096) of each 32 KB slab (16B/lane
      // contiguous runs), sc1 (MALL-coherent); writes LDS with the read
      // swizzle byte ^= ((row&7)<<4), row = byte>>10.
      const u16* sbh = Hhi + (size_t)((t - 1) & 1) * 16384;
      const u16* sbl = Hlo + (size_t)((t - 1) & 1) * 16384;
      uint4 th[8], tl[8];
#pragma unroll
      for (int j = 0; j < 8; ++j) {
        const u16* ph = sbh + tid * 8 + j * 2048;
        const u16* pl = sbl + tid * 8 + j * 2048;
        asm volatile(
            "global_load_dwordx4 %0, %2, off sc1\n\t"
            "global_load_dwordx4 %1, %3, off sc1"
            : "=v"(th[j]), "=v"(tl[j])
            : "v"(ph), "v"(pl)
            : "memory");
      }
      asm volatile("s_waitcnt vmcnt(0)" ::: "memory");
      __builtin_amdgcn_sched_barrier(0);
#pragma unroll
      for (int j = 0; j < 8; ++j) {
        const int L = tid * 16 + j * 4096;
        const int a = L ^ (((L >> 10) & 7) << 4);
        *(uint4*)((char*)HhS + a) = th[j];
        *(uint4*)((char*)HlS + a) = tl[j];
      }
      __syncthreads();

#pragma unroll
      for (int kt = 0; kt < 16; ++kt) {
        const int aoff = (abase_sw + kt * 64 + quad * 16) ^ aswz;
        U4S8 va, vl;
        va.u = *(const uint4*)((const char*)HhS + aoff);
        vl.u = *(const uint4*)((const char*)HlS + aoff);
        acc_hh = __builtin_amdgcn_mfma_f32_16x16x32_bf16(va.s, bhi[kt], acc_hh, 0, 0, 0);
        acc_hl = __builtin_amdgcn_mfma_f32_16x16x32_bf16(va.s, blo[kt], acc_hl, 0, 0, 0);
        acc_lh = __builtin_amdgcn_mfma_f32_16x16x32_bf16(vl.s, bhi[kt], acc_lh, 0, 0, 0);
      }
    }

    // Prefetch next step's G (independent; hides under exchange + barrier).
    if (t + 1 < t1) {
      const int ls = dir ? (511 - (t + 1) - s0) : (t + 1 - s0);
      const size_t goff = (size_t)ls * 65536 + gcol;
      if (gHalf) {
        const __half* Gp = (const __half*)Gv;
        gpre.x = __half2float(Gp[goff + 0]);
        gpre.y = __half2float(Gp[goff + 1]);
        gpre.z = __half2float(Gp[goff + 2]);
        gpre.w = __half2float(Gp[goff + 3]);
      } else {
        const float4 gv = *(const float4*)((const float*)Gv + goff);
        gpre.x = gv.x; gpre.y = gv.y; gpre.z = gv.z; gpre.w = gv.w;
      }
    }

    // exchange: D row (quad*4+r) = batch - mt*16, col l15 -> nl
    {
      const int base = nl * 32 + mt * 16 + quad * 4;
      gl[base + 0] = acc_hh.x + acc_hl.x + acc_lh.x;
      gl[base + 1] = acc_hh.y + acc_hl.y + acc_lh.y;
      gl[base + 2] = acc_hh.z + acc_hl.z + acc_lh.z;
      gl[base + 3] = acc_hh.w + acc_hl.w + acc_lh.w;
    }
    __syncthreads();

    float hval;
    int id;
    {
      const float a0 = gl[(0 * 8 + ciu) * 32 + cb];
      const float a1 = gl[(1 * 8 + ciu) * 32 + cb];
      const float a2 = gl[(2 * 8 + ciu) * 32 + cb];
      const float a3 = gl[(3 * 8 + ciu) * 32 + cb];
      const float ig = sigm(a0), fg = sigm(a1);
      const float gg = tanhf(a2), og = sigm(a3);
      c = fg * c + ig * gg;
      hval = og * tanhf(c);
      const u16 hh = f2bf(hval);
      shh[cb * 8 + ciu] = hh;
      shl[cb * 8 + ciu] = f2bf(hval - bf2f(hh));
      id = ldI(uid, cb * 512 + sidx, is64);
    }
    __syncthreads();

    // Wave 0: re-gather staged h, 128x 8B agent stores (16B runs per batch),
    // one drain, tid0 publishes. Other waves proceed to atomicMax.
    if (tid < 64) {
      const int sb = lane >> 1, q = lane & 1;       // batch, 4-unit chunk
      const u64 vh = ((const u64*)shh)[sb * 2 + q];
      const u64 vo = ((const u64*)shl)[sb * 2 + q];
      const size_t so = (size_t)(t & 1) * 16384 + (size_t)sb * 512 + j0 + q * 4;
      __hip_atomic_store((u64*)(Hhi + so), vh, __ATOMIC_RELAXED, __HIP_MEMORY_SCOPE_AGENT);
      __hip_atomic_store((u64*)(Hlo + so), vo, __ATOMIC_RELAXED, __HIP_MEMORY_SCOPE_AGENT);
      asm volatile("s_waitcnt vmcnt(0)" ::: "memory");
      if (tid == 0)
        __hip_atomic_store(slots + (size_t)wg * 1024, (u32)(t + 1),
                           __ATOMIC_RELAXED, __HIP_MEMORY_SCOPE_AGENT);
    }
    // Deferred fused max-pool: overlaps the next poll.
    if (id > 0 && hval > 0.f)
      atomicMax((int*)&mp[(size_t)(cb * 32 + (id - 1)) * 1024 + dir * 512 + (j0 + ciu)],
                __float_as_int(hval));
  }

  if (t1 < 512) Cb[cb * 512 + j0 + ciu] = c;   // spill c across phase boundary
}

// Fused dual-direction phase kernel: WGs 0..63 = dir0, 64..127 = dir1.
__global__ __launch_bounds__(256) void k_lstm2(
    const void* __restrict__ GA, const void* __restrict__ GB,
    const void* __restrict__ WhhA, const void* __restrict__ WhhB,
    u16* __restrict__ Hh0, u16* __restrict__ Hl0,
    u16* __restrict__ Hh1, u16* __restrict__ Hl1,
    float* __restrict__ Cb, float* __restrict__ mp,
    const void* __restrict__ uid, u32* __restrict__ slots,
    const u32* __restrict__ flags, int gHalf,
    int t0, int t1, int s0A, int s0B)
{
  const int dir = ((int)blockIdx.x >= 64) ? 1 : 0;
  const int wg = (int)blockIdx.x & 63;
  const void* Gv  = dir ? GB : GA;
  const void* Whh = dir ? WhhB : WhhA;
  u16* Hhi = dir ? Hh1 : Hh0;
  u16* Hlo = dir ? Hl1 : Hl0;
  lstm_body(wg, dir, t0, t1, dir ? s0B : s0A, Gv, Whh, Hhi, Hlo,
            Cb + (size_t)dir * 16384, mp, uid,
            slots + (size_t)dir * 65536, flags, gHalf);
}

// ---------------------------------------------------------------------------
// Phase 4a: topic_weights -> twT[k][t] fp32, bias -> fp32.
// ---------------------------------------------------------------------------
__global__ __launch_bounds__(256) void k_prep(
    const void* __restrict__ tw, const void* __restrict__ tb,
    float* __restrict__ twT, float* __restrict__ biasT, const u32* __restrict__ flags)
{
  const int isBF = (int)flags[0];
  const int idx = blockIdx.x * 256 + threadIdx.x;
  if (idx < 102400) {
    const int t = idx >> 10, k = idx & 1023;
    twT[k * 100 + t] = ldF(tw, idx, isBF);
  } else if (idx < 102500) {
    biasT[idx - 102400] = ldF(tb, idx - 102400, isBF);
  }
}

// ---------------------------------------------------------------------------
// Phase 4: per (b,u): logits(100) -> softmax -> emb row (fp32).
// ---------------------------------------------------------------------------
__global__ __launch_bounds__(256) void k_topic(
    const float* __restrict__ mp, const float* __restrict__ twT,
    const float* __restrict__ biasT, const void* __restrict__ table,
    float* __restrict__ emb, const u32* __restrict__ flags)
{
  const int isBF = (int)flags[0];
  const int bu = blockIdx.x;
  const int tid = threadIdx.x;
  __shared__ float lrow[1024];
  __shared__ float red[128];
  __shared__ float parr[128];
  for (int i = tid; i < 1024; i += 256) lrow[i] = mp[(size_t)bu * 1024 + i];
  __syncthreads();
  float lacc = -1e30f;
  if (tid < 100) {
    lacc = biasT[tid];
    for (int k = 0; k < 1024; ++k) lacc = fmaf(lrow[k], twT[k * 100 + tid], lacc);
  }
  if (tid < 128) red[tid] = (tid < 100) ? lacc : -1e30f;
  __syncthreads();
  for (int off = 64; off > 0; off >>= 1) {
    if (tid < off) red[tid] = fmaxf(red[tid], red[tid + off]);
    __syncthreads();
  }
  const float mxv = red[0];
  __syncthreads();
  const float e = (tid < 100) ? expf(lacc - mxv) : 0.f;
  if (tid < 128) red[tid] = e;
  __syncthreads();
  for (int off = 64; off > 0; off >>= 1) {
    if (tid < off) red[tid] += red[tid + off];
    __syncthreads();
  }
  const float inv = 1.f / red[0];
  if (tid < 128) parr[tid] = e * inv;
  __syncthreads();
#pragma unroll
  for (int r = 0; r < 4; ++r) {
    const int w = tid + 256 * r;
    float a = 0.f;
    for (int t = 0; t < 100; ++t)
      a = fmaf(parr[t], ldF(table, (size_t)t * 1024 + w, isBF), a);
    emb[(size_t)bu * 1024 + w] = a;
  }
}

// ---------------------------------------------------------------------------
// Phase 5: out = emb[b][clip(|uid|-1,0,31)][w] * {1,2,0}. Dtype by flag.
// ---------------------------------------------------------------------------
__global__ __launch_bounds__(256) void k_out(
    const float* __restrict__ emb, const void* __restrict__ uid,
    void* __restrict__ outv, const u32* __restrict__ flags)
{
  const int isBF = (int)flags[0];
  const int is64 = (int)flags[1];
  const int idx = blockIdx.x * 256 + threadIdx.x;
  const int w = idx & 1023;
  const int s = (idx >> 10) & 511;
  const int b = idx >> 19;
  const int id = ldI(uid, b * 512 + s, is64);
  const float wt = (id > 0) ? 1.f : ((id < 0) ? 2.f : 0.f);
  int au = (id < 0) ? (-id - 1) : (id - 1);
  au = max(0, min(31, au));
  const float v = emb[(size_t)(b * 32 + au) * 1024 + w] * wt;
  if (isBF) ((u16*)outv)[idx] = f2bf(v);
  else      ((float*)outv)[idx] = v;
}

// ---------------------------------------------------------------------------
// ws layout (phased fused dirs):
//  fp32-G (ws >= 143,934,464; R5 proved >=176.7MB):
//    GA 64Mi | GB 64Mi | Hh0,Hl0,Hh1,Hl1 4x64Ki | Cb 128Ki | mp 4Mi | emb 4Mi
//    | twT 400Ki | biasT 512 | slots 512Ki (128 x 4KB spread) | flags 512
//  fp16-G fallback: GA/GB 32Mi each + same tail ~= 76.8 MB
// ---------------------------------------------------------------------------
extern "C" void kernel_launch(void* const* d_in, const int* in_sizes, int n_in,
                              void* d_out, int out_size, void* d_ws, size_t ws_size,
                              hipStream_t stream) {
  (void)in_sizes; (void)n_in; (void)out_size;
  const void* X    = d_in[0];
  const void* uid  = d_in[1];
  const void* Wihf = d_in[2];
  const void* Whhf = d_in[3];
  const void* bihf = d_in[4];
  const void* bhhf = d_in[5];
  const void* Wihb = d_in[6];
  const void* Whhb = d_in[7];
  const void* bihb = d_in[8];
  const void* bhhb = d_in[9];
  const void* tw   = d_in[10];
  const void* tb   = d_in[11];
  const void* tt   = d_in[12];
  char* ws = (char*)d_ws;

  const int gHalf = (ws_size >= 143934464ull) ? 0 : 1;
  const size_t gB = gHalf ? 33554432ull : 67108864ull;   // per-dir G (256 steps)
  const size_t oGB = gB;
  const size_t oH  = 2ull * gB;
  const size_t oCb = oH + 262144ull;          // 4 slabs x 64Ki
  const size_t omp = oCb + 131072ull;
  const size_t oem = omp + 4194304ull;
  const size_t otw = oem + 4194304ull;
  const size_t obi = otw + 409600ull;
  const size_t osl = obi + 512ull;
  const size_t oFL = osl + 524288ull;

  void*  GA    = (void*)(ws + 0);
  void*  GB    = (void*)(ws + oGB);
  u16*   Hh0   = (u16*)(ws + oH);
  u16*   Hl0   = (u16*)(ws + oH + 65536ull);
  u16*   Hh1   = (u16*)(ws + oH + 131072ull);
  u16*   Hl1   = (u16*)(ws + oH + 196608ull);
  float* Cb    = (float*)(ws + oCb);
  float* mp    = (float*)(ws + omp);
  float* emb   = (float*)(ws + oem);
  float* twT   = (float*)(ws + otw);
  float* biasT = (float*)(ws + obi);
  u32*   slots = (u32*)(ws + osl);
  u32*   flags = (u32*)(ws + oFL);

  (void)hipMemsetAsync(mp, 0, 4194304ull, stream);    // segment-max floor = 0
  (void)hipMemsetAsync(slots, 0, 524288ull, stream);  // barrier slots (spread)
  k_probe<<<1, 256, 0, stream>>>((const u32*)X, (const u32*)uid, flags);

  // Phase A: dir0 s[0,256) -> GA; dir1 s[256,512) -> GB; steps t=0..255.
  k_xproj<<<dim3(128, 32), 256, 0, stream>>>(X, Wihf, bihf, bhhf, GA, flags, gHalf, 0);
  k_xproj<<<dim3(128, 32), 256, 0, stream>>>(X, Wihb, bihb, bhhb, GB, flags, gHalf, 256);
  k_lstm2<<<128, 256, 0, stream>>>(GA, GB, Whhf, Whhb, Hh0, Hl0, Hh1, Hl1,
                                   Cb, mp, uid, slots, flags, gHalf,
                                   0, 256, 0, 256);
  // Phase B: dir0 s[256,512) -> GA; dir1 s[0,256) -> GB; steps t=256..511.
  k_xproj<<<dim3(128, 32), 256, 0, stream>>>(X, Wihf, bihf, bhhf, GA, flags, gHalf, 256);
  k_xproj<<<dim3(128, 32), 256, 0, stream>>>(X, Wihb, bihb, bhhb, GB, flags, gHalf, 0);
  k_lstm2<<<128, 256, 0, stream>>>(GA, GB, Whhf, Whhb, Hh0, Hl0, Hh1, Hl1,
                                   Cb, mp, uid, slots, flags, gHalf,
                                   256, 512, 256, 0);

  k_prep<<<401, 256, 0, stream>>>(tw, tb, twT, biasT, flags);
  k_topic<<<1024, 256, 0, stream>>>(mp, twT, biasT, tt, emb, flags);
  k_out<<<65536, 256, 0, stream>>>(emb, uid, d_out, flags);
}

// Round 15
// 2912.976 us; speedup vs baseline: 2.1618x; 1.0035x over previous
//
#include <hip/hip_runtime.h>
#include <hip/hip_fp16.h>

// GetTopic: biLSTM (B=32,S=512,W=1024,HP=512) -> fused per-utterance segment
// max -> topic softmax (T=100) -> weighted gather. Inputs fp32 (probe kept).
//
// R21 = R20/R18 (2.92 ms, PROVEN; recurrence at practical floor) + two
// stateless-kernel deltas (no sync structure / numerics change):
//  - k_xproj BK 32->64: 64 k-elems staged per round (LDS 4x[64][72], 36KB),
//    2 fragment sub-iters per barrier pair -> half the barriers, 2x MFMA
//    per stage. k-accumulation order unchanged -> bit-identical G.
//  - k_out vectorized: 2048 WGs grid-stride, 8 contiguous elems/thread
//    (one uid load per 8, float4/uint4 IO) vs 65536 WGs x scalar.
// Recurrence (k_lstm2) VERBATIM R18: 64 WGs/dir x 256 thr, sc1 h exchange +
// XOR-swizzled LDS slab stage, 4KB-spread slot barrier, LDS-staged wave0 h
// stores, SSA Whh frags (rule-#20 full unroll), deferred mp atomicMax,
// phased dual-dir execution. (512-thr geometry races at speed - R19.)

typedef unsigned short u16;
typedef unsigned int   u32;
typedef unsigned long long u64;
typedef __attribute__((ext_vector_type(8))) short short8;
typedef __attribute__((ext_vector_type(4))) float float4v;

__device__ __forceinline__ float bf2f(u16 u) { return __uint_as_float(((u32)u) << 16); }
__device__ __forceinline__ u16 f2bf(float f) {
  u32 u = __float_as_uint(f);
  u32 r = u + 0x7FFFu + ((u >> 16) & 1u);   // RNE
  return (u16)(r >> 16);
}
__device__ __forceinline__ float sigm(float x) { return 1.f / (1.f + expf(-x)); }

__device__ __forceinline__ float ldF(const void* p, size_t i, int isBF) {
  return isBF ? bf2f(((const u16*)p)[i]) : ((const float*)p)[i];
}
__device__ __forceinline__ int ldI(const void* p, int i, int is64) {
  return is64 ? (int)((const u32*)p)[(size_t)2 * i] : ((const int*)p)[i];
}

union U4S8 { uint4 u; short8 s; u16 us[8]; };

// ---------------------------------------------------------------------------
// Probe: input storage formats from raw bits (R4/R5-proven).
// flags[0]: 1 = float tensors bf16, 0 = fp32.  flags[1]: 1 = ids int64.
// ---------------------------------------------------------------------------
__global__ __launch_bounds__(256) void k_probe(
    const u32* __restrict__ X, const u32* __restrict__ U, u32* __restrict__ flags)
{
  __shared__ int cnt[2];
  if (threadIdx.x == 0) { cnt[0] = 0; cnt[1] = 0; }
  __syncthreads();
  int c0 = 0;
  for (int i = threadIdx.x; i < 1024; i += 256) {
    const u32 e = (X[i] >> 7) & 0xFFu;
    if (e >= 112u && e <= 143u) c0++;
  }
  int c1 = 0;
  {
    const u32 w = U[2 * threadIdx.x + 1];
    if (w == 0u || w == 0xFFFFFFFFu) c1++;
  }
  atomicAdd(&cnt[0], c0);
  atomicAdd(&cnt[1], c1);
  __syncthreads();
  if (threadIdx.x == 0) {
    flags[0] = (cnt[0] >= 512) ? 1u : 0u;
    flags[1] = (cnt[1] >= 128) ? 1u : 0u;
  }
}

// ---------------------------------------------------------------------------
// Phase 1: G_local[sl][n][b] = x[s0+sl] @ Wih^T + (bih+bhh) for sl in [0,256).
// Split-bf16 MFMA GEMM. M=8192 (m=sl*32+b), N=2048, K=1024.
// R21: BK=64 (2 fragment sub-iters per barrier pair; same k order -> bit-
// identical G vs R20's BK=32).
// ---------------------------------------------------------------------------
__global__ __launch_bounds__(256) void k_xproj(
    const void* __restrict__ X, const void* __restrict__ Wih,
    const void* __restrict__ bih, const void* __restrict__ bhh,
    void* __restrict__ Gv, const u32* __restrict__ flags, int gHalf, int s0)
{
  const int isBF = (int)flags[0];
  const int m0 = blockIdx.x * 64;
  const int n0 = blockIdx.y * 64;
  __shared__ u16 Ah[64][72];   // BK=64, stride 72 u16 (144B)
  __shared__ u16 Al[64][72];
  __shared__ u16 Bh[64][72];
  __shared__ u16 Bl[64][72];
  const int tid = threadIdx.x;
  const int lrow = tid >> 2;          // 0..63: staging row
  const int lkg  = (tid & 3) * 16;    // 16 k-elems per thread per row
  const int lane = tid & 63;
  const int wid  = tid >> 6;          // wave -> M-chunk
  const int l15  = lane & 15;
  const int quad = lane >> 4;
  const int am = m0 + lrow;
  const int ab = am & 31, asl = am >> 5;           // m = sl*32 + b
  const size_t arow = ((size_t)ab * 512 + (s0 + asl)) * 1024;
  const size_t brow = (size_t)(n0 + lrow) * 1024;

  float4v acc[4];
#pragma unroll
  for (int c = 0; c < 4; ++c) {
    acc[c].x = 0.f; acc[c].y = 0.f; acc[c].z = 0.f; acc[c].w = 0.f;
  }

  for (int k0 = 0; k0 < 1024; k0 += 64) {
    float a16[16], b16[16];
    if (isBF) {
      const u16* Xh = (const u16*)X;
      const u16* Wh = (const u16*)Wih;
      uint4 va0 = *(const uint4*)(Xh + arow + k0 + lkg);
      uint4 va1 = *(const uint4*)(Xh + arow + k0 + lkg + 8);
      uint4 vb0 = *(const uint4*)(Wh + brow + k0 + lkg);
      uint4 vb1 = *(const uint4*)(Wh + brow + k0 + lkg + 8);
      const u32 wa[8] = {va0.x, va0.y, va0.z, va0.w, va1.x, va1.y, va1.z, va1.w};
      const u32 wb[8] = {vb0.x, vb0.y, vb0.z, vb0.w, vb1.x, vb1.y, vb1.z, vb1.w};
#pragma unroll
      for (int q = 0; q < 8; ++q) {
        a16[2 * q]     = __uint_as_float(wa[q] << 16);
        a16[2 * q + 1] = __uint_as_float(wa[q] & 0xFFFF0000u);
        b16[2 * q]     = __uint_as_float(wb[q] << 16);
        b16[2 * q + 1] = __uint_as_float(wb[q] & 0xFFFF0000u);
      }
    } else {
      const float* Xf = (const float*)X;
      const float* Wf = (const float*)Wih;
#pragma unroll
      for (int h = 0; h < 4; ++h) {
        const float4 xa = *(const float4*)(Xf + arow + k0 + lkg + 4 * h);
        const float4 xb = *(const float4*)(Wf + brow + k0 + lkg + 4 * h);
        a16[4 * h + 0] = xa.x; a16[4 * h + 1] = xa.y;
        a16[4 * h + 2] = xa.z; a16[4 * h + 3] = xa.w;
        b16[4 * h + 0] = xb.x; b16[4 * h + 1] = xb.y;
        b16[4 * h + 2] = xb.z; b16[4 * h + 3] = xb.w;
      }
    }
    // split to hi/lo bf16 (Sterbenz-exact remainder), stage 2x16B per array
    U4S8 pah0, pah1, pal0, pal1, pbh0, pbh1, pbl0, pbl1;
#pragma unroll
    for (int j = 0; j < 8; ++j) {
      {
        const u16 ah = f2bf(a16[j]);
        pah0.us[j] = ah; pal0.us[j] = f2bf(a16[j] - bf2f(ah));
        const u16 bh = f2bf(b16[j]);
        pbh0.us[j] = bh; pbl0.us[j] = f2bf(b16[j] - bf2f(bh));
      }
      {
        const u16 ah = f2bf(a16[8 + j]);
        pah1.us[j] = ah; pal1.us[j] = f2bf(a16[8 + j] - bf2f(ah));
        const u16 bh = f2bf(b16[8 + j]);
        pbh1.us[j] = bh; pbl1.us[j] = f2bf(b16[8 + j] - bf2f(bh));
      }
    }
    *(uint4*)&Ah[lrow][lkg]     = pah0.u;
    *(uint4*)&Ah[lrow][lkg + 8] = pah1.u;
    *(uint4*)&Al[lrow][lkg]     = pal0.u;
    *(uint4*)&Al[lrow][lkg + 8] = pal1.u;
    *(uint4*)&Bh[lrow][lkg]     = pbh0.u;
    *(uint4*)&Bh[lrow][lkg + 8] = pbh1.u;
    *(uint4*)&Bl[lrow][lkg]     = pbl0.u;
    *(uint4*)&Bl[lrow][lkg + 8] = pbl1.u;
    __syncthreads();

#pragma unroll
    for (int kk = 0; kk < 2; ++kk) {
      U4S8 fah, fal;
      fah.u = *(const uint4*)&Ah[wid * 16 + l15][kk * 32 + quad * 8];
      fal.u = *(const uint4*)&Al[wid * 16 + l15][kk * 32 + quad * 8];
#pragma unroll
      for (int c = 0; c < 4; ++c) {
        U4S8 fbh, fbl;
        fbh.u = *(const uint4*)&Bh[c * 16 + l15][kk * 32 + quad * 8];
        fbl.u = *(const uint4*)&Bl[c * 16 + l15][kk * 32 + quad * 8];
        acc[c] = __builtin_amdgcn_mfma_f32_16x16x32_bf16(fah.s, fbh.s, acc[c], 0, 0, 0);
        acc[c] = __builtin_amdgcn_mfma_f32_16x16x32_bf16(fah.s, fbl.s, acc[c], 0, 0, 0);
        acc[c] = __builtin_amdgcn_mfma_f32_16x16x32_bf16(fal.s, fbh.s, acc[c], 0, 0, 0);
      }
    }
    __syncthreads();
  }

  const int mrow = m0 + wid * 16 + quad * 4;
  const int b0 = mrow & 31, sl = mrow >> 5;
#pragma unroll
  for (int c = 0; c < 4; ++c) {
    const int n = n0 + c * 16 + l15;
    const float bias = ldF(bih, n, isBF) + ldF(bhh, n, isBF);
    const size_t off = ((size_t)sl * 2048 + n) * 32 + b0;
    if (gHalf) {
      ushort4 pk;
      pk.x = __half_as_ushort(__float2half(acc[c].x + bias));
      pk.y = __half_as_ushort(__float2half(acc[c].y + bias));
      pk.z = __half_as_ushort(__float2half(acc[c].z + bias));
      pk.w = __half_as_ushort(__float2half(acc[c].w + bias));
      *(uint2*)((u16*)Gv + off) = *(uint2*)&pk;
    } else {
      float4 pk;
      pk.x = acc[c].x + bias; pk.y = acc[c].y + bias;
      pk.z = acc[c].z + bias; pk.w = acc[c].w + bias;
      *(float4*)((float*)Gv + off) = pk;
    }
  }
}

// ---------------------------------------------------------------------------
// Phase 2 body (R18-proven, VERBATIM). One dir, 64 WGs x 256. WG owns 8
// hidden units = 32 gate cols; Whh register-resident as split-bf16 MFMA
// fragments (setup loop fully unrolled -> SSA, no scratch). Prev-step h
// slabs (64 KB) cooperatively staged into XOR-swizzled LDS.
// ---------------------------------------------------------------------------
__device__ __forceinline__ void lstm_body(
    const int wg, const int dir, const int t0, const int t1, const int s0,
    const void* __restrict__ Gv, const void* __restrict__ Whh,
    u16* __restrict__ Hhi, u16* __restrict__ Hlo, float* __restrict__ Cb,
    float* __restrict__ mp, const void* __restrict__ uid,
    u32* __restrict__ slots, const u32* __restrict__ flags, const int gHalf)
{
  __shared__ float gl[1024];                    // [col32][b32] gate preacts
  __shared__ __align__(16) u16 shh[256];        // staged h hi: [b32][u8]
  __shared__ __align__(16) u16 shl[256];        // staged h lo: [b32][u8]
  __shared__ __align__(16) u16 HhS[16384];      // 32 KB swizzled h-hi slab
  __shared__ __align__(16) u16 HlS[16384];      // 32 KB swizzled h-lo slab
  const int isBF = (int)flags[0];
  const int is64 = (int)flags[1];
  const int tid = threadIdx.x;
  const int j0 = wg * 8;
  const int lane = tid & 63;
  const int wid = tid >> 6;
  const int mt = wid & 1, nt = wid >> 1;
  const int l15 = lane & 15;
  const int quad = lane >> 4;
  const int nl = nt * 16 + l15;        // col 0..31 within WG
  const int n = ((nl >> 3) * 512) + j0 + (nl & 7);   // global gate row/col

  // B-frags: split-bf16 of Whh row n. B[n=l15][k=quad*8+j].
  // FULL unroll -> bhi/blo are SSA register values, not scratch (rule #20).
  short8 bhi[16], blo[16];
#pragma unroll
  for (int kt = 0; kt < 16; ++kt) {
    const int k0 = kt * 32 + quad * 8;
    float w[8];
    if (isBF) {
      const u16* Wh = (const u16*)Whh;
#pragma unroll
      for (int jj = 0; jj < 8; ++jj) w[jj] = bf2f(Wh[(size_t)n * 512 + k0 + jj]);
    } else {
      const float* Wf = (const float*)Whh;
      const float4 w0 = *(const float4*)(Wf + (size_t)n * 512 + k0);
      const float4 w1 = *(const float4*)(Wf + (size_t)n * 512 + k0 + 4);
      w[0] = w0.x; w[1] = w0.y; w[2] = w0.z; w[3] = w0.w;
      w[4] = w1.x; w[5] = w1.y; w[6] = w1.z; w[7] = w1.w;
    }
    U4S8 ph, pl;
#pragma unroll
    for (int jj = 0; jj < 8; ++jj) {
      const u16 hi = f2bf(w[jj]);
      const float rem = w[jj] - bf2f(hi);   // exact (Sterbenz)
      ph.us[jj] = hi; pl.us[jj] = f2bf(rem);
    }
    bhi[kt] = ph.s; blo[kt] = pl.s;
  }

  const int b_a = mt * 16 + l15;        // A row = batch
  const int cb = tid & 31;              // consumer: batch
  const int ciu = tid >> 5;             // consumer: unit 0..7
  float c = (t0 == 0) ? 0.f : Cb[cb * 512 + j0 + ciu];

  // Per-thread G column offset; per-step local offset = ls*65536 + gcol.
  const size_t gcol = (size_t)n * 32 + (size_t)(mt * 16 + quad * 4);

  // Prefetch G for t=t0 (plain cached loads -- L2 stays warm).
  float4v gpre;
  {
    const int ls = dir ? (511 - t0 - s0) : (t0 - s0);
    const size_t goff = (size_t)ls * 65536 + gcol;
    if (gHalf) {
      const __half* Gp = (const __half*)Gv;
      gpre.x = __half2float(Gp[goff + 0]);
      gpre.y = __half2float(Gp[goff + 1]);
      gpre.z = __half2float(Gp[goff + 2]);
      gpre.w = __half2float(Gp[goff + 3]);
    } else {
      const float4 gv = *(const float4*)((const float*)Gv + goff);
      gpre.x = gv.x; gpre.y = gv.y; gpre.z = gv.z; gpre.w = gv.w;
    }
  }

  // A-fragment LDS byte offset (swizzled): row b_a, col byte kt*64+quad*16.
  const int abase_sw = b_a * 1024;
  const int aswz = (b_a & 7) << 4;

  for (int t = t0; t < t1; ++t) {
    const int sidx = dir ? (511 - t) : t;
    if (t > t0) {
      // Parallel detection: lane i of wave 0 polls slot i (4KB spread).
      if (tid < 64) {
        const u32 target = (u32)t;
        const u32* sl = slots + (size_t)lane * 1024;   // 4KB stride
        for (;;) {
          const u32 v = __hip_atomic_load(sl, __ATOMIC_RELAXED, __HIP_MEMORY_SCOPE_AGENT);
          if (__all((int)(v >= target))) break;
          __builtin_amdgcn_s_sleep(1);
        }
      }
      __syncthreads();
    }

    // C-init from prefetched G (4 consecutive batches per lane, col n).
    float4v acc_hh = gpre;
    float4v acc_hl, acc_lh;
    acc_hl.x = 0.f; acc_hl.y = 0.f; acc_hl.z = 0.f; acc_hl.w = 0.f;
    acc_lh.x = 0.f; acc_lh.y = 0.f; acc_lh.z = 0.f; acc_lh.w = 0.f;

    if (t > 0) {
      // Cooperative coalesced stage of prev-step h slabs into LDS.
      // Thread loads bytes [tid*16 + j*4096) of each 32 KB slab (16B/lane
      // contiguous runs), sc1 (MALL-coherent); writes LDS with the read
      // swizzle byte ^= ((row&7)<<4), row = byte>>10.
      const u16* sbh = Hhi + (size_t)((t - 1) & 1) * 16384;
      const u16* sbl = Hlo + (size_t)((t - 1) & 1) * 16384;
      uint4 th[8], tl[8];
#pragma unroll
      for (int j = 0; j < 8; ++j) {
        const u16* ph = sbh + tid * 8 + j * 2048;
        const u16* pl = sbl + tid * 8 + j * 2048;
        asm volatile(
            "global_load_dwordx4 %0, %2, off sc1\n\t"
            "global_load_dwordx4 %1, %3, off sc1"
            : "=v"(th[j]), "=v"(tl[j])
            : "v"(ph), "v"(pl)
            : "memory");
      }
      asm volatile("s_waitcnt vmcnt(0)" ::: "memory");
      __builtin_amdgcn_sched_barrier(0);
#pragma unroll
      for (int j = 0; j < 8; ++j) {
        const int L = tid * 16 + j * 4096;
        const int a = L ^ (((L >> 10) & 7) << 4);
        *(uint4*)((char*)HhS + a) = th[j];
        *(uint4*)((char*)HlS + a) = tl[j];
      }
      __syncthreads();

#pragma unroll
      for (int kt = 0; kt < 16; ++kt) {
        const int aoff = (abase_sw + kt * 64 + quad * 16) ^ aswz;
        U4S8 va, vl;
        va.u = *(const uint4*)((const char*)HhS + aoff);
        vl.u = *(const uint4*)((const char*)HlS + aoff);
        acc_hh = __builtin_amdgcn_mfma_f32_16x16x32_bf16(va.s, bhi[kt], acc_hh, 0, 0, 0);
        acc_hl = __builtin_amdgcn_mfma_f32_16x16x32_bf16(va.s, blo[kt], acc_hl, 0, 0, 0);
        acc_lh = __builtin_amdgcn_mfma_f32_16x16x32_bf16(vl.s, bhi[kt], acc_lh, 0, 0, 0);
      }
    }

    // Prefetch next step's G (independent; hides under exchange + barrier).
    if (t + 1 < t1) {
      const int ls = dir ? (511 - (t + 1) - s0) : (t + 1 - s0);
      const size_t goff = (size_t)ls * 65536 + gcol;
      if (gHalf) {
        const __half* Gp = (const __half*)Gv;
        gpre.x = __half2float(Gp[goff + 0]);
        gpre.y = __half2float(Gp[goff + 1]);
        gpre.z = __half2float(Gp[goff + 2]);
        gpre.w = __half2float(Gp[goff + 3]);
      } else {
        const float4 gv = *(const float4*)((const float*)Gv + goff);
        gpre.x = gv.x; gpre.y = gv.y; gpre.z = gv.z; gpre.w = gv.w;
      }
    }

    // exchange: D row (quad*4+r) = batch - mt*16, col l15 -> nl
    {
      const int base = nl * 32 + mt * 16 + quad * 4;
      gl[base + 0] = acc_hh.x + acc_hl.x + acc_lh.x;
      gl[base + 1] = acc_hh.y + acc_hl.y + acc_lh.y;
      gl[base + 2] = acc_hh.z + acc_hl.z + acc_lh.z;
      gl[base + 3] = acc_hh.w + acc_hl.w + acc_lh.w;
    }
    __syncthreads();

    float hval;
    int id;
    {
      const float a0 = gl[(0 * 8 + ciu) * 32 + cb];
      const float a1 = gl[(1 * 8 + ciu) * 32 + cb];
      const float a2 = gl[(2 * 8 + ciu) * 32 + cb];
      const float a3 = gl[(3 * 8 + ciu) * 32 + cb];
      const float ig = sigm(a0), fg = sigm(a1);
      const float gg = tanhf(a2), og = sigm(a3);
      c = fg * c + ig * gg;
      hval = og * tanhf(c);
      const u16 hh = f2bf(hval);
      shh[cb * 8 + ciu] = hh;
      shl[cb * 8 + ciu] = f2bf(hval - bf2f(hh));
      id = ldI(uid, cb * 512 + sidx, is64);
    }
    __syncthreads();

    // Wave 0: re-gather staged h, 128x 8B agent stores (16B runs per batch),
    // one drain, tid0 publishes. Other waves proceed to atomicMax.
    if (tid < 64) {
      const int sb = lane >> 1, q = lane & 1;       // batch, 4-unit chunk
      const u64 vh = ((const u64*)shh)[sb * 2 + q];
      const u64 vo = ((const u64*)shl)[sb * 2 + q];
      const size_t so = (size_t)(t & 1) * 16384 + (size_t)sb * 512 + j0 + q * 4;
      __hip_atomic_store((u64*)(Hhi + so), vh, __ATOMIC_RELAXED, __HIP_MEMORY_SCOPE_AGENT);
      __hip_atomic_store((u64*)(Hlo + so), vo, __ATOMIC_RELAXED, __HIP_MEMORY_SCOPE_AGENT);
      asm volatile("s_waitcnt vmcnt(0)" ::: "memory");
      if (tid == 0)
        __hip_atomic_store(slots + (size_t)wg * 1024, (u32)(t + 1),
                           __ATOMIC_RELAXED, __HIP_MEMORY_SCOPE_AGENT);
    }
    // Deferred fused max-pool: overlaps the next poll.
    if (id > 0 && hval > 0.f)
      atomicMax((int*)&mp[(size_t)(cb * 32 + (id - 1)) * 1024 + dir * 512 + (j0 + ciu)],
                __float_as_int(hval));
  }

  if (t1 < 512) Cb[cb * 512 + j0 + ciu] = c;   // spill c across phase boundary
}

// Fused dual-direction phase kernel: WGs 0..63 = dir0, 64..127 = dir1.
__global__ __launch_bounds__(256) void k_lstm2(
    const void* __restrict__ GA, const void* __restrict__ GB,
    const void* __restrict__ WhhA, const void* __restrict__ WhhB,
    u16* __restrict__ Hh0, u16* __restrict__ Hl0,
    u16* __restrict__ Hh1, u16* __restrict__ Hl1,
    float* __restrict__ Cb, float* __restrict__ mp,
    const void* __restrict__ uid, u32* __restrict__ slots,
    const u32* __restrict__ flags, int gHalf,
    int t0, int t1, int s0A, int s0B)
{
  const int dir = ((int)blockIdx.x >= 64) ? 1 : 0;
  const int wg = (int)blockIdx.x & 63;
  const void* Gv  = dir ? GB : GA;
  const void* Whh = dir ? WhhB : WhhA;
  u16* Hhi = dir ? Hh1 : Hh0;
  u16* Hlo = dir ? Hl1 : Hl0;
  lstm_body(wg, dir, t0, t1, dir ? s0B : s0A, Gv, Whh, Hhi, Hlo,
            Cb + (size_t)dir * 16384, mp, uid,
            slots + (size_t)dir * 65536, flags, gHalf);
}

// ---------------------------------------------------------------------------
// Phase 4a: topic_weights -> twT[k][t] fp32, bias -> fp32.
// ---------------------------------------------------------------------------
__global__ __launch_bounds__(256) void k_prep(
    const void* __restrict__ tw, const void* __restrict__ tb,
    float* __restrict__ twT, float* __restrict__ biasT, const u32* __restrict__ flags)
{
  const int isBF = (int)flags[0];
  const int idx = blockIdx.x * 256 + threadIdx.x;
  if (idx < 102400) {
    const int t = idx >> 10, k = idx & 1023;
    twT[k * 100 + t] = ldF(tw, idx, isBF);
  } else if (idx < 102500) {
    biasT[idx - 102400] = ldF(tb, idx - 102400, isBF);
  }
}

// ---------------------------------------------------------------------------
// Phase 4: per (b,u): logits(100) -> softmax -> emb row (fp32).
// ---------------------------------------------------------------------------
__global__ __launch_bounds__(256) void k_topic(
    const float* __restrict__ mp, const float* __restrict__ twT,
    const float* __restrict__ biasT, const void* __restrict__ table,
    float* __restrict__ emb, const u32* __restrict__ flags)
{
  const int isBF = (int)flags[0];
  const int bu = blockIdx.x;
  const int tid = threadIdx.x;
  __shared__ float lrow[1024];
  __shared__ float red[128];
  __shared__ float parr[128];
  for (int i = tid; i < 1024; i += 256) lrow[i] = mp[(size_t)bu * 1024 + i];
  __syncthreads();
  float lacc = -1e30f;
  if (tid < 100) {
    lacc = biasT[tid];
    for (int k = 0; k < 1024; ++k) lacc = fmaf(lrow[k], twT[k * 100 + tid], lacc);
  }
  if (tid < 128) red[tid] = (tid < 100) ? lacc : -1e30f;
  __syncthreads();
  for (int off = 64; off > 0; off >>= 1) {
    if (tid < off) red[tid] = fmaxf(red[tid], red[tid + off]);
    __syncthreads();
  }
  const float mxv = red[0];
  __syncthreads();
  const float e = (tid < 100) ? expf(lacc - mxv) : 0.f;
  if (tid < 128) red[tid] = e;
  __syncthreads();
  for (int off = 64; off > 0; off >>= 1) {
    if (tid < off) red[tid] += red[tid + off];
    __syncthreads();
  }
  const float inv = 1.f / red[0];
  if (tid < 128) parr[tid] = e * inv;
  __syncthreads();
#pragma unroll
  for (int r = 0; r < 4; ++r) {
    const int w = tid + 256 * r;
    float a = 0.f;
    for (int t = 0; t < 100; ++t)
      a = fmaf(parr[t], ldF(table, (size_t)t * 1024 + w, isBF), a);
    emb[(size_t)bu * 1024 + w] = a;
  }
}

// ---------------------------------------------------------------------------
// Phase 5: out = emb[b][clip(|uid|-1,0,31)][w] * {1,2,0}. Dtype by flag.
// R21: vectorized grid-stride, 8 contiguous elems/thread (same (b,s) per 8).
// ---------------------------------------------------------------------------
__global__ __launch_bounds__(256) void k_out(
    const float* __restrict__ emb, const void* __restrict__ uid,
    void* __restrict__ outv, const u32* __restrict__ flags)
{
  const int isBF = (int)flags[0];
  const int is64 = (int)flags[1];
  for (int idx = ((int)blockIdx.x * 256 + (int)threadIdx.x) * 8;
       idx < 16777216; idx += 2048 * 256 * 8) {
    const int w = idx & 1023;
    const int s = (idx >> 10) & 511;
    const int b = idx >> 19;
    const int id = ldI(uid, b * 512 + s, is64);
    const float wt = (id > 0) ? 1.f : ((id < 0) ? 2.f : 0.f);
    int au = (id < 0) ? (-id - 1) : (id - 1);
    au = max(0, min(31, au));
    const float* e = &emb[(size_t)(b * 32 + au) * 1024 + w];
    float4 v0 = *(const float4*)(e);
    float4 v1 = *(const float4*)(e + 4);
    v0.x *= wt; v0.y *= wt; v0.z *= wt; v0.w *= wt;
    v1.x *= wt; v1.y *= wt; v1.z *= wt; v1.w *= wt;
    if (isBF) {
      U4S8 pk;
      pk.us[0] = f2bf(v0.x); pk.us[1] = f2bf(v0.y);
      pk.us[2] = f2bf(v0.z); pk.us[3] = f2bf(v0.w);
      pk.us[4] = f2bf(v1.x); pk.us[5] = f2bf(v1.y);
      pk.us[6] = f2bf(v1.z); pk.us[7] = f2bf(v1.w);
      *(uint4*)((u16*)outv + idx) = pk.u;
    } else {
      *(float4*)((float*)outv + idx)     = v0;
      *(float4*)((float*)outv + idx + 4) = v1;
    }
  }
}

// ---------------------------------------------------------------------------
// ws layout (phased fused dirs):
//  fp32-G (ws >= 143,934,464; R5 proved >=176.7MB):
//    GA 64Mi | GB 64Mi | Hh0,Hl0,Hh1,Hl1 4x64Ki | Cb 128Ki | mp 4Mi | emb 4Mi
//    | twT 400Ki | biasT 512 | slots 512Ki (128 x 4KB spread) | flags 512
//  fp16-G fallback: GA/GB 32Mi each + same tail ~= 76.8 MB
// ---------------------------------------------------------------------------
extern "C" void kernel_launch(void* const* d_in, const int* in_sizes, int n_in,
                              void* d_out, int out_size, void* d_ws, size_t ws_size,
                              hipStream_t stream) {
  (void)in_sizes; (void)n_in; (void)out_size;
  const void* X    = d_in[0];
  const void* uid  = d_in[1];
  const void* Wihf = d_in[2];
  const void* Whhf = d_in[3];
  const void* bihf = d_in[4];
  const void* bhhf = d_in[5];
  const void* Wihb = d_in[6];
  const void* Whhb = d_in[7];
  const void* bihb = d_in[8];
  const void* bhhb = d_in[9];
  const void* tw   = d_in[10];
  const void* tb   = d_in[11];
  const void* tt   = d_in[12];
  char* ws = (char*)d_ws;

  const int gHalf = (ws_size >= 143934464ull) ? 0 : 1;
  const size_t gB = gHalf ? 33554432ull : 67108864ull;   // per-dir G (256 steps)
  const size_t oGB = gB;
  const size_t oH  = 2ull * gB;
  const size_t oCb = oH + 262144ull;          // 4 slabs x 64Ki
  const size_t omp = oCb + 131072ull;
  const size_t oem = omp + 4194304ull;
  const size_t otw = oem + 4194304ull;
  const size_t obi = otw + 409600ull;
  const size_t osl = obi + 512ull;
  const size_t oFL = osl + 524288ull;

  void*  GA    = (void*)(ws + 0);
  void*  GB    = (void*)(ws + oGB);
  u16*   Hh0   = (u16*)(ws + oH);
  u16*   Hl0   = (u16*)(ws + oH + 65536ull);
  u16*   Hh1   = (u16*)(ws + oH + 131072ull);
  u16*   Hl1   = (u16*)(ws + oH + 196608ull);
  float* Cb    = (float*)(ws + oCb);
  float* mp    = (float*)(ws + omp);
  float* emb   = (float*)(ws + oem);
  float* twT   = (float*)(ws + otw);
  float* biasT = (float*)(ws + obi);
  u32*   slots = (u32*)(ws + osl);
  u32*   flags = (u32*)(ws + oFL);

  (void)hipMemsetAsync(mp, 0, 4194304ull, stream);    // segment-max floor = 0
  (void)hipMemsetAsync(slots, 0, 524288ull, stream);  // barrier slots (spread)
  k_probe<<<1, 256, 0, stream>>>((const u32*)X, (const u32*)uid, flags);

  // Phase A: dir0 s[0,256) -> GA; dir1 s[256,512) -> GB; steps t=0..255.
  k_xproj<<<dim3(128, 32), 256, 0, stream>>>(X, Wihf, bihf, bhhf, GA, flags, gHalf, 0);
  k_xproj<<<dim3(128, 32), 256, 0, stream>>>(X, Wihb, bihb, bhhb, GB, flags, gHalf, 256);
  k_lstm2<<<128, 256, 0, stream>>>(GA, GB, Whhf, Whhb, Hh0, Hl0, Hh1, Hl1,
                                   Cb, mp, uid, slots, flags, gHalf,
                                   0, 256, 0, 256);
  // Phase B: dir0 s[256,512) -> GA; dir1 s[0,256) -> GB; steps t=256..511.
  k_xproj<<<dim3(128, 32), 256, 0, stream>>>(X, Wihf, bihf, bhhf, GA, flags, gHalf, 256);
  k_xproj<<<dim3(128, 32), 256, 0, stream>>>(X, Wihb, bihb, bhhb, GB, flags, gHalf, 0);
  k_lstm2<<<128, 256, 0, stream>>>(GA, GB, Whhf, Whhb, Hh0, Hl0, Hh1, Hl1,
                                   Cb, mp, uid, slots, flags, gHalf,
                                   256, 512, 256, 0);

  k_prep<<<401, 256, 0, stream>>>(tw, tb, twT, biasT, flags);
  k_topic<<<1024, 256, 0, stream>>>(mp, twT, biasT, tt, emb, flags);
  k_out<<<2048, 256, 0, stream>>>(emb, uid, d_out, flags);
}

// Round 16
// 2876.196 us; speedup vs baseline: 2.1895x; 1.0128x over previous
//
#include <hip/hip_runtime.h>
#include <hip/hip_fp16.h>

// GetTopic: biLSTM (B=32,S=512,W=1024,HP=512) -> fused per-utterance segment
// max -> topic softmax (T=100) -> weighted gather. Inputs fp32 (probe kept).
//
// R22 = R21 (2.91 ms) + ONE delta: Wih split-bf16 conversion HOISTED out of
// k_xproj. R21 post-mortem: BK=64 was flat because xproj is conversion-
// VALU-bound (~200 VALU ops/thread/iter for f2bf splits vs ~120 cyc MFMA);
// the B-operand (Wih) is re-converted 128x (once per m0-block). k_wsplit
// precomputes Whi/Wlo ONCE (memory-bound, ~10 us); k_xproj B-path is now
// straight uint4 loads -> LDS. Same f2bf math -> bit-identical G.
// +16 MB ws (160.7 MB < 176.7 MB proven).
// Recurrence (k_lstm2) VERBATIM R18 (proven floor): 64 WGs/dir x 256 thr,
// sc1 h exchange + XOR-swizzled LDS slab stage, 4KB-spread slot barrier,
// LDS-staged wave0 h stores, SSA Whh frags, deferred mp atomicMax, phased
// dual-dir execution. k_out vectorized (R21).

typedef unsigned short u16;
typedef unsigned int   u32;
typedef unsigned long long u64;
typedef __attribute__((ext_vector_type(8))) short short8;
typedef __attribute__((ext_vector_type(4))) float float4v;

__device__ __forceinline__ float bf2f(u16 u) { return __uint_as_float(((u32)u) << 16); }
__device__ __forceinline__ u16 f2bf(float f) {
  u32 u = __float_as_uint(f);
  u32 r = u + 0x7FFFu + ((u >> 16) & 1u);   // RNE
  return (u16)(r >> 16);
}
__device__ __forceinline__ float sigm(float x) { return 1.f / (1.f + expf(-x)); }

__device__ __forceinline__ float ldF(const void* p, size_t i, int isBF) {
  return isBF ? bf2f(((const u16*)p)[i]) : ((const float*)p)[i];
}
__device__ __forceinline__ int ldI(const void* p, int i, int is64) {
  return is64 ? (int)((const u32*)p)[(size_t)2 * i] : ((const int*)p)[i];
}

union U4S8 { uint4 u; short8 s; u16 us[8]; };

// ---------------------------------------------------------------------------
// Probe: input storage formats from raw bits (R4/R5-proven).
// flags[0]: 1 = float tensors bf16, 0 = fp32.  flags[1]: 1 = ids int64.
// ---------------------------------------------------------------------------
__global__ __launch_bounds__(256) void k_probe(
    const u32* __restrict__ X, const u32* __restrict__ U, u32* __restrict__ flags)
{
  __shared__ int cnt[2];
  if (threadIdx.x == 0) { cnt[0] = 0; cnt[1] = 0; }
  __syncthreads();
  int c0 = 0;
  for (int i = threadIdx.x; i < 1024; i += 256) {
    const u32 e = (X[i] >> 7) & 0xFFu;
    if (e >= 112u && e <= 143u) c0++;
  }
  int c1 = 0;
  {
    const u32 w = U[2 * threadIdx.x + 1];
    if (w == 0u || w == 0xFFFFFFFFu) c1++;
  }
  atomicAdd(&cnt[0], c0);
  atomicAdd(&cnt[1], c1);
  __syncthreads();
  if (threadIdx.x == 0) {
    flags[0] = (cnt[0] >= 512) ? 1u : 0u;
    flags[1] = (cnt[1] >= 128) ? 1u : 0u;
  }
}

// ---------------------------------------------------------------------------
// Phase 0b: Wih -> split-bf16 (Whi, Wlo). 2048x1024 elems, 8/thread.
// Same f2bf split used everywhere -> downstream results bit-identical.
// ---------------------------------------------------------------------------
__global__ __launch_bounds__(256) void k_wsplit(
    const void* __restrict__ W, u16* __restrict__ Whi, u16* __restrict__ Wlo,
    const u32* __restrict__ flags)
{
  const int isBF = (int)flags[0];
  const int base = ((int)blockIdx.x * 256 + (int)threadIdx.x) * 8;
  U4S8 ph, pl;
#pragma unroll
  for (int j = 0; j < 8; ++j) {
    const float w = ldF(W, (size_t)base + j, isBF);
    const u16 hi = f2bf(w);
    ph.us[j] = hi;
    pl.us[j] = f2bf(w - bf2f(hi));   // exact (Sterbenz)
  }
  *(uint4*)(Whi + base) = ph.u;
  *(uint4*)(Wlo + base) = pl.u;
}

// ---------------------------------------------------------------------------
// Phase 1: G_local[sl][n][b] = x[s0+sl] @ Wih^T + (bih+bhh) for sl in [0,256).
// Split-bf16 MFMA GEMM, BK=64. M=8192 (m=sl*32+b), N=2048, K=1024.
// R22: B-operand read PRE-SPLIT (Whi/Wlo) -> no B-side conversion VALU.
// ---------------------------------------------------------------------------
__global__ __launch_bounds__(256) void k_xproj(
    const void* __restrict__ X,
    const u16* __restrict__ Whi, const u16* __restrict__ Wlo,
    const void* __restrict__ bih, const void* __restrict__ bhh,
    void* __restrict__ Gv, const u32* __restrict__ flags, int gHalf, int s0)
{
  const int isBF = (int)flags[0];
  const int m0 = blockIdx.x * 64;
  const int n0 = blockIdx.y * 64;
  __shared__ u16 Ah[64][72];   // BK=64, stride 72 u16 (144B)
  __shared__ u16 Al[64][72];
  __shared__ u16 Bh[64][72];
  __shared__ u16 Bl[64][72];
  const int tid = threadIdx.x;
  const int lrow = tid >> 2;          // 0..63: staging row
  const int lkg  = (tid & 3) * 16;    // 16 k-elems per thread per row
  const int lane = tid & 63;
  const int wid  = tid >> 6;          // wave -> M-chunk
  const int l15  = lane & 15;
  const int quad = lane >> 4;
  const int am = m0 + lrow;
  const int ab = am & 31, asl = am >> 5;           // m = sl*32 + b
  const size_t arow = ((size_t)ab * 512 + (s0 + asl)) * 1024;
  const size_t brow = (size_t)(n0 + lrow) * 1024;

  float4v acc[4];
#pragma unroll
  for (int c = 0; c < 4; ++c) {
    acc[c].x = 0.f; acc[c].y = 0.f; acc[c].z = 0.f; acc[c].w = 0.f;
  }

  for (int k0 = 0; k0 < 1024; k0 += 64) {
    // ----- A: load + split (X stays in input precision) -----
    float a16[16];
    if (isBF) {
      const u16* Xh = (const u16*)X;
      uint4 va0 = *(const uint4*)(Xh + arow + k0 + lkg);
      uint4 va1 = *(const uint4*)(Xh + arow + k0 + lkg + 8);
      const u32 wa[8] = {va0.x, va0.y, va0.z, va0.w, va1.x, va1.y, va1.z, va1.w};
#pragma unroll
      for (int q = 0; q < 8; ++q) {
        a16[2 * q]     = __uint_as_float(wa[q] << 16);
        a16[2 * q + 1] = __uint_as_float(wa[q] & 0xFFFF0000u);
      }
    } else {
      const float* Xf = (const float*)X;
#pragma unroll
      for (int h = 0; h < 4; ++h) {
        const float4 xa = *(const float4*)(Xf + arow + k0 + lkg + 4 * h);
        a16[4 * h + 0] = xa.x; a16[4 * h + 1] = xa.y;
        a16[4 * h + 2] = xa.z; a16[4 * h + 3] = xa.w;
      }
    }
    U4S8 pah0, pah1, pal0, pal1;
#pragma unroll
    for (int j = 0; j < 8; ++j) {
      {
        const u16 ah = f2bf(a16[j]);
        pah0.us[j] = ah; pal0.us[j] = f2bf(a16[j] - bf2f(ah));
      }
      {
        const u16 ah = f2bf(a16[8 + j]);
        pah1.us[j] = ah; pal1.us[j] = f2bf(a16[8 + j] - bf2f(ah));
      }
    }
    *(uint4*)&Ah[lrow][lkg]     = pah0.u;
    *(uint4*)&Ah[lrow][lkg + 8] = pah1.u;
    *(uint4*)&Al[lrow][lkg]     = pal0.u;
    *(uint4*)&Al[lrow][lkg + 8] = pal1.u;

    // ----- B: pre-split, straight loads -> LDS (zero conversion) -----
    {
      const size_t bro = brow + k0 + lkg;
      *(uint4*)&Bh[lrow][lkg]     = *(const uint4*)(Whi + bro);
      *(uint4*)&Bh[lrow][lkg + 8] = *(const uint4*)(Whi + bro + 8);
      *(uint4*)&Bl[lrow][lkg]     = *(const uint4*)(Wlo + bro);
      *(uint4*)&Bl[lrow][lkg + 8] = *(const uint4*)(Wlo + bro + 8);
    }
    __syncthreads();

#pragma unroll
    for (int kk = 0; kk < 2; ++kk) {
      U4S8 fah, fal;
      fah.u = *(const uint4*)&Ah[wid * 16 + l15][kk * 32 + quad * 8];
      fal.u = *(const uint4*)&Al[wid * 16 + l15][kk * 32 + quad * 8];
#pragma unroll
      for (int c = 0; c < 4; ++c) {
        U4S8 fbh, fbl;
        fbh.u = *(const uint4*)&Bh[c * 16 + l15][kk * 32 + quad * 8];
        fbl.u = *(const uint4*)&Bl[c * 16 + l15][kk * 32 + quad * 8];
        acc[c] = __builtin_amdgcn_mfma_f32_16x16x32_bf16(fah.s, fbh.s, acc[c], 0, 0, 0);
        acc[c] = __builtin_amdgcn_mfma_f32_16x16x32_bf16(fah.s, fbl.s, acc[c], 0, 0, 0);
        acc[c] = __builtin_amdgcn_mfma_f32_16x16x32_bf16(fal.s, fbh.s, acc[c], 0, 0, 0);
      }
    }
    __syncthreads();
  }

  const int mrow = m0 + wid * 16 + quad * 4;
  const int b0 = mrow & 31, sl = mrow >> 5;
#pragma unroll
  for (int c = 0; c < 4; ++c) {
    const int n = n0 + c * 16 + l15;
    const float bias = ldF(bih, n, isBF) + ldF(bhh, n, isBF);
    const size_t off = ((size_t)sl * 2048 + n) * 32 + b0;
    if (gHalf) {
      ushort4 pk;
      pk.x = __half_as_ushort(__float2half(acc[c].x + bias));
      pk.y = __half_as_ushort(__float2half(acc[c].y + bias));
      pk.z = __half_as_ushort(__float2half(acc[c].z + bias));
      pk.w = __half_as_ushort(__float2half(acc[c].w + bias));
      *(uint2*)((u16*)Gv + off) = *(uint2*)&pk;
    } else {
      float4 pk;
      pk.x = acc[c].x + bias; pk.y = acc[c].y + bias;
      pk.z = acc[c].z + bias; pk.w = acc[c].w + bias;
      *(float4*)((float*)Gv + off) = pk;
    }
  }
}

// ---------------------------------------------------------------------------
// Phase 2 body (R18-proven, VERBATIM). One dir, 64 WGs x 256. WG owns 8
// hidden units = 32 gate cols; Whh register-resident as split-bf16 MFMA
// fragments (setup loop fully unrolled -> SSA, no scratch). Prev-step h
// slabs (64 KB) cooperatively staged into XOR-swizzled LDS.
// ---------------------------------------------------------------------------
__device__ __forceinline__ void lstm_body(
    const int wg, const int dir, const int t0, const int t1, const int s0,
    const void* __restrict__ Gv, const void* __restrict__ Whh,
    u16* __restrict__ Hhi, u16* __restrict__ Hlo, float* __restrict__ Cb,
    float* __restrict__ mp, const void* __restrict__ uid,
    u32* __restrict__ slots, const u32* __restrict__ flags, const int gHalf)
{
  __shared__ float gl[1024];                    // [col32][b32] gate preacts
  __shared__ __align__(16) u16 shh[256];        // staged h hi: [b32][u8]
  __shared__ __align__(16) u16 shl[256];        // staged h lo: [b32][u8]
  __shared__ __align__(16) u16 HhS[16384];      // 32 KB swizzled h-hi slab
  __shared__ __align__(16) u16 HlS[16384];      // 32 KB swizzled h-lo slab
  const int isBF = (int)flags[0];
  const int is64 = (int)flags[1];
  const int tid = threadIdx.x;
  const int j0 = wg * 8;
  const int lane = tid & 63;
  const int wid = tid >> 6;
  const int mt = wid & 1, nt = wid >> 1;
  const int l15 = lane & 15;
  const int quad = lane >> 4;
  const int nl = nt * 16 + l15;        // col 0..31 within WG
  const int n = ((nl >> 3) * 512) + j0 + (nl & 7);   // global gate row/col

  // B-frags: split-bf16 of Whh row n. B[n=l15][k=quad*8+j].
  // FULL unroll -> bhi/blo are SSA register values, not scratch (rule #20).
  short8 bhi[16], blo[16];
#pragma unroll
  for (int kt = 0; kt < 16; ++kt) {
    const int k0 = kt * 32 + quad * 8;
    float w[8];
    if (isBF) {
      const u16* Wh = (const u16*)Whh;
#pragma unroll
      for (int jj = 0; jj < 8; ++jj) w[jj] = bf2f(Wh[(size_t)n * 512 + k0 + jj]);
    } else {
      const float* Wf = (const float*)Whh;
      const float4 w0 = *(const float4*)(Wf + (size_t)n * 512 + k0);
      const float4 w1 = *(const float4*)(Wf + (size_t)n * 512 + k0 + 4);
      w[0] = w0.x; w[1] = w0.y; w[2] = w0.z; w[3] = w0.w;
      w[4] = w1.x; w[5] = w1.y; w[6] = w1.z; w[7] = w1.w;
    }
    U4S8 ph, pl;
#pragma unroll
    for (int jj = 0; jj < 8; ++jj) {
      const u16 hi = f2bf(w[jj]);
      const float rem = w[jj] - bf2f(hi);   // exact (Sterbenz)
      ph.us[jj] = hi; pl.us[jj] = f2bf(rem);
    }
    bhi[kt] = ph.s; blo[kt] = pl.s;
  }

  const int b_a = mt * 16 + l15;        // A row = batch
  const int cb = tid & 31;              // consumer: batch
  const int ciu = tid >> 5;             // consumer: unit 0..7
  float c = (t0 == 0) ? 0.f : Cb[cb * 512 + j0 + ciu];

  // Per-thread G column offset; per-step local offset = ls*65536 + gcol.
  const size_t gcol = (size_t)n * 32 + (size_t)(mt * 16 + quad * 4);

  // Prefetch G for t=t0 (plain cached loads -- L2 stays warm).
  float4v gpre;
  {
    const int ls = dir ? (511 - t0 - s0) : (t0 - s0);
    const size_t goff = (size_t)ls * 65536 + gcol;
    if (gHalf) {
      const __half* Gp = (const __half*)Gv;
      gpre.x = __half2float(Gp[goff + 0]);
      gpre.y = __half2float(Gp[goff + 1]);
      gpre.z = __half2float(Gp[goff + 2]);
      gpre.w = __half2float(Gp[goff + 3]);
    } else {
      const float4 gv = *(const float4*)((const float*)Gv + goff);
      gpre.x = gv.x; gpre.y = gv.y; gpre.z = gv.z; gpre.w = gv.w;
    }
  }

  // A-fragment LDS byte offset (swizzled): row b_a, col byte kt*64+quad*16.
  const int abase_sw = b_a * 1024;
  const int aswz = (b_a & 7) << 4;

  for (int t = t0; t < t1; ++t) {
    const int sidx = dir ? (511 - t) : t;
    if (t > t0) {
      // Parallel detection: lane i of wave 0 polls slot i (4KB spread).
      if (tid < 64) {
        const u32 target = (u32)t;
        const u32* sl = slots + (size_t)lane * 1024;   // 4KB stride
        for (;;) {
          const u32 v = __hip_atomic_load(sl, __ATOMIC_RELAXED, __HIP_MEMORY_SCOPE_AGENT);
          if (__all((int)(v >= target))) break;
          __builtin_amdgcn_s_sleep(1);
        }
      }
      __syncthreads();
    }

    // C-init from prefetched G (4 consecutive batches per lane, col n).
    float4v acc_hh = gpre;
    float4v acc_hl, acc_lh;
    acc_hl.x = 0.f; acc_hl.y = 0.f; acc_hl.z = 0.f; acc_hl.w = 0.f;
    acc_lh.x = 0.f; acc_lh.y = 0.f; acc_lh.z = 0.f; acc_lh.w = 0.f;

    if (t > 0) {
      // Cooperative coalesced stage of prev-step h slabs into LDS.
      // Thread loads bytes [tid*16 + j*4096) of each 32 KB slab (16B/lane
      // contiguous runs), sc1 (MALL-coherent); writes LDS with the read
      // swizzle byte ^= ((row&7)<<4), row = byte>>10.
      const u16* sbh = Hhi + (size_t)((t - 1) & 1) * 16384;
      const u16* sbl = Hlo + (size_t)((t - 1) & 1) * 16384;
      uint4 th[8], tl[8];
#pragma unroll
      for (int j = 0; j < 8; ++j) {
        const u16* ph = sbh + tid * 8 + j * 2048;
        const u16* pl = sbl + tid * 8 + j * 2048;
        asm volatile(
            "global_load_dwordx4 %0, %2, off sc1\n\t"
            "global_load_dwordx4 %1, %3, off sc1"
            : "=v"(th[j]), "=v"(tl[j])
            : "v"(ph), "v"(pl)
            : "memory");
      }
      asm volatile("s_waitcnt vmcnt(0)" ::: "memory");
      __builtin_amdgcn_sched_barrier(0);
#pragma unroll
      for (int j = 0; j < 8; ++j) {
        const int L = tid * 16 + j * 4096;
        const int a = L ^ (((L >> 10) & 7) << 4);
        *(uint4*)((char*)HhS + a) = th[j];
        *(uint4*)((char*)HlS + a) = tl[j];
      }
      __syncthreads();

#pragma unroll
      for (int kt = 0; kt < 16; ++kt) {
        const int aoff = (abase_sw + kt * 64 + quad * 16) ^ aswz;
        U4S8 va, vl;
        va.u = *(const uint4*)((const char*)HhS + aoff);
        vl.u = *(const uint4*)((const char*)HlS + aoff);
        acc_hh = __builtin_amdgcn_mfma_f32_16x16x32_bf16(va.s, bhi[kt], acc_hh, 0, 0, 0);
        acc_hl = __builtin_amdgcn_mfma_f32_16x16x32_bf16(va.s, blo[kt], acc_hl, 0, 0, 0);
        acc_lh = __builtin_amdgcn_mfma_f32_16x16x32_bf16(vl.s, bhi[kt], acc_lh, 0, 0, 0);
      }
    }

    // Prefetch next step's G (independent; hides under exchange + barrier).
    if (t + 1 < t1) {
      const int ls = dir ? (511 - (t + 1) - s0) : (t + 1 - s0);
      const size_t goff = (size_t)ls * 65536 + gcol;
      if (gHalf) {
        const __half* Gp = (const __half*)Gv;
        gpre.x = __half2float(Gp[goff + 0]);
        gpre.y = __half2float(Gp[goff + 1]);
        gpre.z = __half2float(Gp[goff + 2]);
        gpre.w = __half2float(Gp[goff + 3]);
      } else {
        const float4 gv = *(const float4*)((const float*)Gv + goff);
        gpre.x = gv.x; gpre.y = gv.y; gpre.z = gv.z; gpre.w = gv.w;
      }
    }

    // exchange: D row (quad*4+r) = batch - mt*16, col l15 -> nl
    {
      const int base = nl * 32 + mt * 16 + quad * 4;
      gl[base + 0] = acc_hh.x + acc_hl.x + acc_lh.x;
      gl[base + 1] = acc_hh.y + acc_hl.y + acc_lh.y;
      gl[base + 2] = acc_hh.z + acc_hl.z + acc_lh.z;
      gl[base + 3] = acc_hh.w + acc_hl.w + acc_lh.w;
    }
    __syncthreads();

    float hval;
    int id;
    {
      const float a0 = gl[(0 * 8 + ciu) * 32 + cb];
      const float a1 = gl[(1 * 8 + ciu) * 32 + cb];
      const float a2 = gl[(2 * 8 + ciu) * 32 + cb];
      const float a3 = gl[(3 * 8 + ciu) * 32 + cb];
      const float ig = sigm(a0), fg = sigm(a1);
      const float gg = tanhf(a2), og = sigm(a3);
      c = fg * c + ig * gg;
      hval = og * tanhf(c);
      const u16 hh = f2bf(hval);
      shh[cb * 8 + ciu] = hh;
      shl[cb * 8 + ciu] = f2bf(hval - bf2f(hh));
      id = ldI(uid, cb * 512 + sidx, is64);
    }
    __syncthreads();

    // Wave 0: re-gather staged h, 128x 8B agent stores (16B runs per batch),
    // one drain, tid0 publishes. Other waves proceed to atomicMax.
    if (tid < 64) {
      const int sb = lane >> 1, q = lane & 1;       // batch, 4-unit chunk
      const u64 vh = ((const u64*)shh)[sb * 2 + q];
      const u64 vo = ((const u64*)shl)[sb * 2 + q];
      const size_t so = (size_t)(t & 1) * 16384 + (size_t)sb * 512 + j0 + q * 4;
      __hip_atomic_store((u64*)(Hhi + so), vh, __ATOMIC_RELAXED, __HIP_MEMORY_SCOPE_AGENT);
      __hip_atomic_store((u64*)(Hlo + so), vo, __ATOMIC_RELAXED, __HIP_MEMORY_SCOPE_AGENT);
      asm volatile("s_waitcnt vmcnt(0)" ::: "memory");
      if (tid == 0)
        __hip_atomic_store(slots + (size_t)wg * 1024, (u32)(t + 1),
                           __ATOMIC_RELAXED, __HIP_MEMORY_SCOPE_AGENT);
    }
    // Deferred fused max-pool: overlaps the next poll.
    if (id > 0 && hval > 0.f)
      atomicMax((int*)&mp[(size_t)(cb * 32 + (id - 1)) * 1024 + dir * 512 + (j0 + ciu)],
                __float_as_int(hval));
  }

  if (t1 < 512) Cb[cb * 512 + j0 + ciu] = c;   // spill c across phase boundary
}

// Fused dual-direction phase kernel: WGs 0..63 = dir0, 64..127 = dir1.
__global__ __launch_bounds__(256) void k_lstm2(
    const void* __restrict__ GA, const void* __restrict__ GB,
    const void* __restrict__ WhhA, const void* __restrict__ WhhB,
    u16* __restrict__ Hh0, u16* __restrict__ Hl0,
    u16* __restrict__ Hh1, u16* __restrict__ Hl1,
    float* __restrict__ Cb, float* __restrict__ mp,
    const void* __restrict__ uid, u32* __restrict__ slots,
    const u32* __restrict__ flags, int gHalf,
    int t0, int t1, int s0A, int s0B)
{
  const int dir = ((int)blockIdx.x >= 64) ? 1 : 0;
  const int wg = (int)blockIdx.x & 63;
  const void* Gv  = dir ? GB : GA;
  const void* Whh = dir ? WhhB : WhhA;
  u16* Hhi = dir ? Hh1 : Hh0;
  u16* Hlo = dir ? Hl1 : Hl0;
  lstm_body(wg, dir, t0, t1, dir ? s0B : s0A, Gv, Whh, Hhi, Hlo,
            Cb + (size_t)dir * 16384, mp, uid,
            slots + (size_t)dir * 65536, flags, gHalf);
}

// ---------------------------------------------------------------------------
// Phase 4a: topic_weights -> twT[k][t] fp32, bias -> fp32.
// ---------------------------------------------------------------------------
__global__ __launch_bounds__(256) void k_prep(
    const void* __restrict__ tw, const void* __restrict__ tb,
    float* __restrict__ twT, float* __restrict__ biasT, const u32* __restrict__ flags)
{
  const int isBF = (int)flags[0];
  const int idx = blockIdx.x * 256 + threadIdx.x;
  if (idx < 102400) {
    const int t = idx >> 10, k = idx & 1023;
    twT[k * 100 + t] = ldF(tw, idx, isBF);
  } else if (idx < 102500) {
    biasT[idx - 102400] = ldF(tb, idx - 102400, isBF);
  }
}

// ---------------------------------------------------------------------------
// Phase 4: per (b,u): logits(100) -> softmax -> emb row (fp32).
// ---------------------------------------------------------------------------
__global__ __launch_bounds__(256) void k_topic(
    const float* __restrict__ mp, const float* __restrict__ twT,
    const float* __restrict__ biasT, const void* __restrict__ table,
    float* __restrict__ emb, const u32* __restrict__ flags)
{
  const int isBF = (int)flags[0];
  const int bu = blockIdx.x;
  const int tid = threadIdx.x;
  __shared__ float lrow[1024];
  __shared__ float red[128];
  __shared__ float parr[128];
  for (int i = tid; i < 1024; i += 256) lrow[i] = mp[(size_t)bu * 1024 + i];
  __syncthreads();
  float lacc = -1e30f;
  if (tid < 100) {
    lacc = biasT[tid];
    for (int k = 0; k < 1024; ++k) lacc = fmaf(lrow[k], twT[k * 100 + tid], lacc);
  }
  if (tid < 128) red[tid] = (tid < 100) ? lacc : -1e30f;
  __syncthreads();
  for (int off = 64; off > 0; off >>= 1) {
    if (tid < off) red[tid] = fmaxf(red[tid], red[tid + off]);
    __syncthreads();
  }
  const float mxv = red[0];
  __syncthreads();
  const float e = (tid < 100) ? expf(lacc - mxv) : 0.f;
  if (tid < 128) red[tid] = e;
  __syncthreads();
  for (int off = 64; off > 0; off >>= 1) {
    if (tid < off) red[tid] += red[tid + off];
    __syncthreads();
  }
  const float inv = 1.f / red[0];
  if (tid < 128) parr[tid] = e * inv;
  __syncthreads();
#pragma unroll
  for (int r = 0; r < 4; ++r) {
    const int w = tid + 256 * r;
    float a = 0.f;
    for (int t = 0; t < 100; ++t)
      a = fmaf(parr[t], ldF(table, (size_t)t * 1024 + w, isBF), a);
    emb[(size_t)bu * 1024 + w] = a;
  }
}

// ---------------------------------------------------------------------------
// Phase 5: out = emb[b][clip(|uid|-1,0,31)][w] * {1,2,0}. Dtype by flag.
// Vectorized grid-stride, 8 contiguous elems/thread (same (b,s) per 8).
// ---------------------------------------------------------------------------
__global__ __launch_bounds__(256) void k_out(
    const float* __restrict__ emb, const void* __restrict__ uid,
    void* __restrict__ outv, const u32* __restrict__ flags)
{
  const int isBF = (int)flags[0];
  const int is64 = (int)flags[1];
  for (int idx = ((int)blockIdx.x * 256 + (int)threadIdx.x) * 8;
       idx < 16777216; idx += 2048 * 256 * 8) {
    const int w = idx & 1023;
    const int s = (idx >> 10) & 511;
    const int b = idx >> 19;
    const int id = ldI(uid, b * 512 + s, is64);
    const float wt = (id > 0) ? 1.f : ((id < 0) ? 2.f : 0.f);
    int au = (id < 0) ? (-id - 1) : (id - 1);
    au = max(0, min(31, au));
    const float* e = &emb[(size_t)(b * 32 + au) * 1024 + w];
    float4 v0 = *(const float4*)(e);
    float4 v1 = *(const float4*)(e + 4);
    v0.x *= wt; v0.y *= wt; v0.z *= wt; v0.w *= wt;
    v1.x *= wt; v1.y *= wt; v1.z *= wt; v1.w *= wt;
    if (isBF) {
      U4S8 pk;
      pk.us[0] = f2bf(v0.x); pk.us[1] = f2bf(v0.y);
      pk.us[2] = f2bf(v0.z); pk.us[3] = f2bf(v0.w);
      pk.us[4] = f2bf(v1.x); pk.us[5] = f2bf(v1.y);
      pk.us[6] = f2bf(v1.z); pk.us[7] = f2bf(v1.w);
      *(uint4*)((u16*)outv + idx) = pk.u;
    } else {
      *(float4*)((float*)outv + idx)     = v0;
      *(float4*)((float*)outv + idx + 4) = v1;
    }
  }
}

// ---------------------------------------------------------------------------
// ws layout (phased fused dirs):
//  fp32-G (ws >= 160,711,680; R5 proved >=176.7MB):
//    GA 64Mi | GB 64Mi | Hh0,Hl0,Hh1,Hl1 4x64Ki | Cb 128Ki | mp 4Mi | emb 4Mi
//    | twT 400Ki | biasT 512 | slots 512Ki | flags 512
//    | Wfh 4Mi | Wfl 4Mi | Wbh 4Mi | Wbl 4Mi
//  fp16-G fallback: GA/GB 32Mi each + same tail ~= 93.6 MB
// ---------------------------------------------------------------------------
extern "C" void kernel_launch(void* const* d_in, const int* in_sizes, int n_in,
                              void* d_out, int out_size, void* d_ws, size_t ws_size,
                              hipStream_t stream) {
  (void)in_sizes; (void)n_in; (void)out_size;
  const void* X    = d_in[0];
  const void* uid  = d_in[1];
  const void* Wihf = d_in[2];
  const void* Whhf = d_in[3];
  const void* bihf = d_in[4];
  const void* bhhf = d_in[5];
  const void* Wihb = d_in[6];
  const void* Whhb = d_in[7];
  const void* bihb = d_in[8];
  const void* bhhb = d_in[9];
  const void* tw   = d_in[10];
  const void* tb   = d_in[11];
  const void* tt   = d_in[12];
  char* ws = (char*)d_ws;

  const int gHalf = (ws_size >= 160711680ull) ? 0 : 1;
  const size_t gB = gHalf ? 33554432ull : 67108864ull;   // per-dir G (256 steps)
  const size_t oGB = gB;
  const size_t oH  = 2ull * gB;
  const size_t oCb = oH + 262144ull;          // 4 slabs x 64Ki
  const size_t omp = oCb + 131072ull;
  const size_t oem = omp + 4194304ull;
  const size_t otw = oem + 4194304ull;
  const size_t obi = otw + 409600ull;
  const size_t osl = obi + 512ull;
  const size_t oFL = osl + 524288ull;
  const size_t oWf = oFL + 512ull;            // Wih split buffers (4 x 4Mi)

  void*  GA    = (void*)(ws + 0);
  void*  GB    = (void*)(ws + oGB);
  u16*   Hh0   = (u16*)(ws + oH);
  u16*   Hl0   = (u16*)(ws + oH + 65536ull);
  u16*   Hh1   = (u16*)(ws + oH + 131072ull);
  u16*   Hl1   = (u16*)(ws + oH + 196608ull);
  float* Cb    = (float*)(ws + oCb);
  float* mp    = (float*)(ws + omp);
  float* emb   = (float*)(ws + oem);
  float* twT   = (float*)(ws + otw);
  float* biasT = (float*)(ws + obi);
  u32*   slots = (u32*)(ws + osl);
  u32*   flags = (u32*)(ws + oFL);
  u16*   Wfh   = (u16*)(ws + oWf);
  u16*   Wfl   = (u16*)(ws + oWf + 4194304ull);
  u16*   Wbh   = (u16*)(ws + oWf + 8388608ull);
  u16*   Wbl   = (u16*)(ws + oWf + 12582912ull);

  (void)hipMemsetAsync(mp, 0, 4194304ull, stream);    // segment-max floor = 0
  (void)hipMemsetAsync(slots, 0, 524288ull, stream);  // barrier slots (spread)
  k_probe<<<1, 256, 0, stream>>>((const u32*)X, (const u32*)uid, flags);

  // Phase 0b: pre-split Wih (both dirs) to hi/lo bf16 (hoists the 128x-
  // redundant per-GEMM-block conversion out of k_xproj).
  k_wsplit<<<1024, 256, 0, stream>>>(Wihf, Wfh, Wfl, flags);
  k_wsplit<<<1024, 256, 0, stream>>>(Wihb, Wbh, Wbl, flags);

  // Phase A: dir0 s[0,256) -> GA; dir1 s[256,512) -> GB; steps t=0..255.
  k_xproj<<<dim3(128, 32), 256, 0, stream>>>(X, Wfh, Wfl, bihf, bhhf, GA, flags, gHalf, 0);
  k_xproj<<<dim3(128, 32), 256, 0, stream>>>(X, Wbh, Wbl, bihb, bhhb, GB, flags, gHalf, 256);
  k_lstm2<<<128, 256, 0, stream>>>(GA, GB, Whhf, Whhb, Hh0, Hl0, Hh1, Hl1,
                                   Cb, mp, uid, slots, flags, gHalf,
                                   0, 256, 0, 256);
  // Phase B: dir0 s[256,512) -> GA; dir1 s[0,256) -> GB; steps t=256..511.
  k_xproj<<<dim3(128, 32), 256, 0, stream>>>(X, Wfh, Wfl, bihf, bhhf, GA, flags, gHalf, 256);
  k_xproj<<<dim3(128, 32), 256, 0, stream>>>(X, Wbh, Wbl, bihb, bhhb, GB, flags, gHalf, 0);
  k_lstm2<<<128, 256, 0, stream>>>(GA, GB, Whhf, Whhb, Hh0, Hl0, Hh1, Hl1,
                                   Cb, mp, uid, slots, flags, gHalf,
                                   256, 512, 256, 0);

  k_prep<<<401, 256, 0, stream>>>(tw, tb, twT, biasT, flags);
  k_topic<<<1024, 256, 0, stream>>>(mp, twT, biasT, tt, emb, flags);
  k_out<<<2048, 256, 0, stream>>>(emb, uid, d_out, flags);
}